// Round 3
// baseline (2519.037 us; speedup 1.0000x reference)
//
#include <hip/hip_runtime.h>
#include <hip/hip_bf16.h>

// Problem constants
#define BATCH 2
#define SEQ 2048
#define DM 1024      // d_model
#define DI 2048      // d_inner
#define DS 16        // d_state
#define DR 64        // dt_rank
#define XPC 96       // dt_rank + 2*d_state
#define ROWS 4096    // BATCH*SEQ

// ---------------- generic fp32 tiled GEMM with optional bias ----------------
// C[M,N] = A[M,K] @ B[K,N] + bias[N], with leading dims lda/ldb/ldc
#define GBM 64
#define GBN 64
#define GBK 16

__global__ __launch_bounds__(256) void gemm_f32_bias(
    const float* __restrict__ A, const float* __restrict__ B,
    const float* __restrict__ bias, float* __restrict__ C,
    int M, int N, int K, int lda, int ldb, int ldc)
{
    __shared__ float As[GBK][GBM + 4];
    __shared__ float Bs[GBK][GBN + 4];
    const int tid = threadIdx.x;
    const int bm = blockIdx.y, bn = blockIdx.x;
    const int ty = tid / 16, tx = tid % 16;

    const int a_row = tid / 4;         // 0..63
    const int a_col = (tid % 4) * 4;   // 0,4,8,12
    const int b_row = tid / 16;        // 0..15
    const int b_col = (tid % 16) * 4;  // 0..60

    const float* Ap = A + (size_t)(bm * GBM + a_row) * lda + a_col;
    const float* Bp = B + (size_t)b_row * ldb + bn * GBN + b_col;

    float acc[4][4] = {};

    for (int k0 = 0; k0 < K; k0 += GBK) {
        float4 av = *(const float4*)(Ap + k0);
        float4 bv = *(const float4*)(Bp + (size_t)k0 * ldb);
        As[a_col + 0][a_row] = av.x;
        As[a_col + 1][a_row] = av.y;
        As[a_col + 2][a_row] = av.z;
        As[a_col + 3][a_row] = av.w;
        *(float4*)&Bs[b_row][b_col] = bv;
        __syncthreads();
#pragma unroll
        for (int k = 0; k < GBK; ++k) {
            float a[4], b[4];
#pragma unroll
            for (int i = 0; i < 4; ++i) a[i] = As[k][ty * 4 + i];
#pragma unroll
            for (int j = 0; j < 4; ++j) b[j] = Bs[k][tx * 4 + j];
#pragma unroll
            for (int i = 0; i < 4; ++i)
#pragma unroll
                for (int j = 0; j < 4; ++j) acc[i][j] += a[i] * b[j];
        }
        __syncthreads();
    }

#pragma unroll
    for (int i = 0; i < 4; ++i) {
        int row = bm * GBM + ty * 4 + i;
#pragma unroll
        for (int j = 0; j < 4; ++j) {
            int col = bn * GBN + tx * 4 + j;
            float v = acc[i][j];
            if (bias) v += bias[col];
            C[(size_t)row * ldc + col] = v;
        }
    }
}

// ---------------- depthwise causal conv (width 4) + SiLU ----------------
// xc[r,d] = silu( sum_k xv[r-3+k, d] * cw[d,k] + cb[d] )
__global__ __launch_bounds__(256) void conv_silu_kernel(
    const float* __restrict__ xv, const float* __restrict__ cw,
    const float* __restrict__ cb, float* __restrict__ xc)
{
    int idx = blockIdx.x * 256 + threadIdx.x;   // over ROWS*DI
    int r = idx >> 11;          // /DI (2048)
    int d = idx & (DI - 1);
    int t = r & (SEQ - 1);      // position within batch
    float acc = cb[d];
#pragma unroll
    for (int k = 0; k < 4; ++k) {
        int tt = t - 3 + k;
        if (tt >= 0)
            acc += xv[(size_t)(r - 3 + k) * DI + d] * cw[d * 4 + k];
    }
    float sv = acc / (1.f + __expf(-acc));
    xc[idx] = sv;
}

// ---------------- x_proj: (ROWS x DI) @ (DI x 96) ----------------
// one block does 8 rows; K-chunked LDS staging (16 KB)
__global__ __launch_bounds__(256) void xproj_kernel(
    const float* __restrict__ xc, const float* __restrict__ W,
    float* __restrict__ xdbl)
{
    __shared__ float rows[8][512];
    const int rb = blockIdx.x * 8;
    const int tid = threadIdx.x;
    float acc[3] = {0.f, 0.f, 0.f};
    for (int k0 = 0; k0 < DI; k0 += 512) {
        for (int i = tid; i < 1024; i += 256) {     // 1024 float4 = 8x512
            int off = i * 4;
            int rr = off >> 9, cc = off & 511;
            *(float4*)&rows[rr][cc] =
                *(const float4*)(xc + (size_t)(rb + rr) * DI + k0 + cc);
        }
        __syncthreads();
#pragma unroll
        for (int j = 0; j < 3; ++j) {
            int o = tid + j * 256;                  // 0..767
            int rr = o / XPC, cc = o % XPC;
            float a = 0.f;
#pragma unroll 4
            for (int k = 0; k < 512; ++k)
                a += rows[rr][k] * W[(size_t)(k0 + k) * XPC + cc];
            acc[j] += a;
        }
        __syncthreads();
    }
#pragma unroll
    for (int j = 0; j < 3; ++j) {
        int o = tid + j * 256;
        int rr = o / XPC, cc = o % XPC;
        xdbl[(size_t)(rb + rr) * XPC + cc] = acc[j];
    }
}

// ---------------- dt_proj + softplus: (ROWS x 64) @ (64 x DI) ----------------
__global__ __launch_bounds__(256) void dtproj_kernel(
    const float* __restrict__ xdbl, const float* __restrict__ W,
    const float* __restrict__ bias, float* __restrict__ dt)
{
    __shared__ float rows[8][DR];
    const int rb = (blockIdx.x / 8) * 8;
    const int cb0 = (blockIdx.x % 8) * 256;
    const int tid = threadIdx.x;
    if (tid < 128) {
        int rr = tid / 16, cc = (tid % 16) * 4;
        float4 v = *(const float4*)(xdbl + (size_t)(rb + rr) * XPC + cc);
        *(float4*)&rows[rr][cc] = v;
    }
    __syncthreads();
    const int col = cb0 + tid;
    float acc[8] = {};
    for (int k = 0; k < DR; ++k) {
        float w = W[(size_t)k * DI + col];
#pragma unroll
        for (int rr = 0; rr < 8; ++rr) acc[rr] += rows[rr][k] * w;
    }
    float b = bias[col];
#pragma unroll
    for (int rr = 0; rr < 8; ++rr) {
        float z = acc[rr] + b;
        float sp = (z > 20.f) ? z : log1pf(__expf(z));
        dt[(size_t)(rb + rr) * DI + col] = sp;
    }
}

// ---------------- selective scan (+D skip, + silu(res) gating) ----------------
// 16 lanes per (b,d): lane n holds state h[n]. Reduce y over n with shfl_xor.
// yg is written IN PLACE over dt (safe: same-wave, same-iteration load->store).
__global__ __launch_bounds__(256) void scan_kernel(
    float* __restrict__ dt_yg, const float* __restrict__ xc,
    const float* __restrict__ xdbl, const float* __restrict__ res,
    const float* __restrict__ logA, const float* __restrict__ Dp)
{
    const int gid = blockIdx.x * 256 + threadIdx.x;
    const int n = gid & (DS - 1);
    const int pair = gid >> 4;        // (b,d)
    const int d = pair & (DI - 1);
    const int b = pair >> 11;
    const float A_dn = -__expf(logA[d * DS + n]);
    const float Dd = Dp[d];
    float h = 0.f;
    const int base_r = b * SEQ;
    for (int t = 0; t < SEQ; ++t) {
        const int r = base_r + t;
        float dtv = dt_yg[(size_t)r * DI + d];
        float xv = xc[(size_t)r * DI + d];
        float Bv = xdbl[(size_t)r * XPC + DR + n];
        float Cv = xdbl[(size_t)r * XPC + DR + DS + n];
        float dA = __expf(dtv * A_dn);
        h = dA * h + (dtv * xv) * Bv;
        float p = h * Cv;
        p += __shfl_xor(p, 1);
        p += __shfl_xor(p, 2);
        p += __shfl_xor(p, 4);
        p += __shfl_xor(p, 8);
        if (n == 0) {
            float y = p + xv * Dd;
            float rv = res[(size_t)r * DI + d];
            float sr = rv / (1.f + __expf(-rv));
            dt_yg[(size_t)r * DI + d] = y * sr;
        }
    }
}

extern "C" void kernel_launch(void* const* d_in, const int* in_sizes, int n_in,
                              void* d_out, int out_size, void* d_ws, size_t ws_size,
                              hipStream_t stream) {
    const float* x          = (const float*)d_in[0];
    const float* in_proj_w  = (const float*)d_in[1];
    const float* in_proj_b  = (const float*)d_in[2];
    const float* conv_w     = (const float*)d_in[3];
    const float* conv_b     = (const float*)d_in[4];
    const float* x_proj_w   = (const float*)d_in[5];
    const float* dt_proj_w  = (const float*)d_in[6];
    const float* dt_proj_b  = (const float*)d_in[7];
    const float* log_A      = (const float*)d_in[8];
    const float* Dp         = (const float*)d_in[9];
    const float* out_proj_w = (const float*)d_in[10];
    const float* out_proj_b = (const float*)d_in[11];

    // Workspace layout (floats): 97.5 MB total
    float* ws   = (float*)d_ws;
    float* bufA = ws;                           // ROWS*DI: x_val raw -> dt -> yg
    float* res  = bufA + (size_t)ROWS * DI;     // ROWS*DI: res half
    float* xc   = res  + (size_t)ROWS * DI;     // ROWS*DI: conv+silu output
    float* xdbl = xc   + (size_t)ROWS * DI;     // ROWS*XPC

    dim3 blk(256);

    // 1) in_proj split into two N=2048 halves: x_val -> bufA, res -> res
    gemm_f32_bias<<<dim3(DI / GBN, ROWS / GBM), blk, 0, stream>>>(
        x, in_proj_w, in_proj_b, bufA, ROWS, DI, DM, DM, 2 * DI, DI);
    gemm_f32_bias<<<dim3(DI / GBN, ROWS / GBM), blk, 0, stream>>>(
        x, in_proj_w + DI, in_proj_b + DI, res, ROWS, DI, DM, DM, 2 * DI, DI);

    // 2) conv + silu: bufA -> xc   (bufA's raw x_val is dead afterwards)
    conv_silu_kernel<<<(ROWS * DI) / 256, blk, 0, stream>>>(bufA, conv_w, conv_b, xc);

    // 3) x_proj: xc -> xdbl
    xproj_kernel<<<ROWS / 8, blk, 0, stream>>>(xc, x_proj_w, xdbl);

    // 4) dt_proj + softplus: xdbl -> bufA (reused as dt)
    dtproj_kernel<<<(ROWS / 8) * (DI / 256), blk, 0, stream>>>(
        xdbl, dt_proj_w, dt_proj_b, bufA);

    // 5) selective scan + gating: writes yg in place over dt (bufA)
    scan_kernel<<<(BATCH * DI * DS) / 256, blk, 0, stream>>>(
        bufA, xc, xdbl, res, log_A, Dp);

    // 6) out_proj: bufA(ROWS x DI) @ out_proj_w(DI x DM) + b -> out   [K = DI!]
    gemm_f32_bias<<<dim3(DM / GBN, ROWS / GBM), blk, 0, stream>>>(
        bufA, out_proj_w, out_proj_b, (float*)d_out, ROWS, DM, DI, DI, DM, DM);
}

// Round 4
// 1154.232 us; speedup vs baseline: 2.1824x; 2.1824x over previous
//
#include <hip/hip_runtime.h>
#include <hip/hip_bf16.h>

// Problem constants
#define BATCH 2
#define SEQ 2048
#define DM 1024      // d_model
#define DI 2048      // d_inner
#define DS 16        // d_state
#define DR 64        // dt_rank
#define XPC 96       // dt_rank + 2*d_state
#define ROWS 4096    // BATCH*SEQ
#define NC 32        // scan chunks per sequence
#define CL 64        // chunk length = SEQ/NC

// ---------------- generic fp32 tiled GEMM with optional bias ----------------
// C[M,N] = A[M,K] @ B[K,N] + bias[N], with leading dims lda/ldb/ldc
#define GBM 64
#define GBN 64
#define GBK 16

__global__ __launch_bounds__(256) void gemm_f32_bias(
    const float* __restrict__ A, const float* __restrict__ B,
    const float* __restrict__ bias, float* __restrict__ C,
    int M, int N, int K, int lda, int ldb, int ldc)
{
    __shared__ float As[GBK][GBM + 4];
    __shared__ float Bs[GBK][GBN + 4];
    const int tid = threadIdx.x;
    const int bm = blockIdx.y, bn = blockIdx.x;
    const int ty = tid / 16, tx = tid % 16;

    const int a_row = tid / 4;         // 0..63
    const int a_col = (tid % 4) * 4;   // 0,4,8,12
    const int b_row = tid / 16;        // 0..15
    const int b_col = (tid % 16) * 4;  // 0..60

    const float* Ap = A + (size_t)(bm * GBM + a_row) * lda + a_col;
    const float* Bp = B + (size_t)b_row * ldb + bn * GBN + b_col;

    float acc[4][4] = {};

    for (int k0 = 0; k0 < K; k0 += GBK) {
        float4 av = *(const float4*)(Ap + k0);
        float4 bv = *(const float4*)(Bp + (size_t)k0 * ldb);
        As[a_col + 0][a_row] = av.x;
        As[a_col + 1][a_row] = av.y;
        As[a_col + 2][a_row] = av.z;
        As[a_col + 3][a_row] = av.w;
        *(float4*)&Bs[b_row][b_col] = bv;
        __syncthreads();
#pragma unroll
        for (int k = 0; k < GBK; ++k) {
            float a[4], b[4];
#pragma unroll
            for (int i = 0; i < 4; ++i) a[i] = As[k][ty * 4 + i];
#pragma unroll
            for (int j = 0; j < 4; ++j) b[j] = Bs[k][tx * 4 + j];
#pragma unroll
            for (int i = 0; i < 4; ++i)
#pragma unroll
                for (int j = 0; j < 4; ++j) acc[i][j] += a[i] * b[j];
        }
        __syncthreads();
    }

#pragma unroll
    for (int i = 0; i < 4; ++i) {
        int row = bm * GBM + ty * 4 + i;
#pragma unroll
        for (int j = 0; j < 4; ++j) {
            int col = bn * GBN + tx * 4 + j;
            float v = acc[i][j];
            if (bias) v += bias[col];
            C[(size_t)row * ldc + col] = v;
        }
    }
}

// ---------------- depthwise causal conv (width 4) + SiLU ----------------
__global__ __launch_bounds__(256) void conv_silu_kernel(
    const float* __restrict__ xv, const float* __restrict__ cw,
    const float* __restrict__ cb, float* __restrict__ xc)
{
    int idx = blockIdx.x * 256 + threadIdx.x;   // over ROWS*DI
    int r = idx >> 11;          // /DI (2048)
    int d = idx & (DI - 1);
    int t = r & (SEQ - 1);      // position within batch
    float acc = cb[d];
#pragma unroll
    for (int k = 0; k < 4; ++k) {
        int tt = t - 3 + k;
        if (tt >= 0)
            acc += xv[(size_t)(r - 3 + k) * DI + d] * cw[d * 4 + k];
    }
    float sv = acc / (1.f + __expf(-acc));
    xc[idx] = sv;
}

// ---------------- x_proj: (ROWS x DI) @ (DI x 96) ----------------
__global__ __launch_bounds__(256) void xproj_kernel(
    const float* __restrict__ xc, const float* __restrict__ W,
    float* __restrict__ xdbl)
{
    __shared__ float rows[8][512];
    const int rb = blockIdx.x * 8;
    const int tid = threadIdx.x;
    float acc[3] = {0.f, 0.f, 0.f};
    for (int k0 = 0; k0 < DI; k0 += 512) {
        for (int i = tid; i < 1024; i += 256) {     // 1024 float4 = 8x512
            int off = i * 4;
            int rr = off >> 9, cc = off & 511;
            *(float4*)&rows[rr][cc] =
                *(const float4*)(xc + (size_t)(rb + rr) * DI + k0 + cc);
        }
        __syncthreads();
#pragma unroll
        for (int j = 0; j < 3; ++j) {
            int o = tid + j * 256;                  // 0..767
            int rr = o / XPC, cc = o % XPC;
            float a = 0.f;
#pragma unroll 4
            for (int k = 0; k < 512; ++k)
                a += rows[rr][k] * W[(size_t)(k0 + k) * XPC + cc];
            acc[j] += a;
        }
        __syncthreads();
    }
#pragma unroll
    for (int j = 0; j < 3; ++j) {
        int o = tid + j * 256;
        int rr = o / XPC, cc = o % XPC;
        xdbl[(size_t)(rb + rr) * XPC + cc] = acc[j];
    }
}

// ---------------- dt_proj + softplus: (ROWS x 64) @ (64 x DI) ----------------
__global__ __launch_bounds__(256) void dtproj_kernel(
    const float* __restrict__ xdbl, const float* __restrict__ W,
    const float* __restrict__ bias, float* __restrict__ dt)
{
    __shared__ float rows[8][DR];
    const int rb = (blockIdx.x / 8) * 8;
    const int cb0 = (blockIdx.x % 8) * 256;
    const int tid = threadIdx.x;
    if (tid < 128) {
        int rr = tid / 16, cc = (tid % 16) * 4;
        float4 v = *(const float4*)(xdbl + (size_t)(rb + rr) * XPC + cc);
        *(float4*)&rows[rr][cc] = v;
    }
    __syncthreads();
    const int col = cb0 + tid;
    float acc[8] = {};
    for (int k = 0; k < DR; ++k) {
        float w = W[(size_t)k * DI + col];
#pragma unroll
        for (int rr = 0; rr < 8; ++rr) acc[rr] += rows[rr][k] * w;
    }
    float b = bias[col];
#pragma unroll
    for (int rr = 0; rr < 8; ++rr) {
        float z = acc[rr] + b;
        float sp = (z > 20.f) ? z : log1pf(__expf(z));
        dt[(size_t)(rb + rr) * DI + col] = sp;
    }
}

// ---------------- chunked selective scan ----------------
// Pass 1: per (b,chunk,d) thread, 16 states in registers, local scan from 0.
// Stores hend[(b*NC+c)*DS+n][d] and prodA (= exp(A*sum(dt))).
__global__ __launch_bounds__(256) void scan_pass1(
    const float* __restrict__ dt, const float* __restrict__ xc,
    const float* __restrict__ xdbl, const float* __restrict__ logA,
    float* __restrict__ hend, float* __restrict__ prodA)
{
    const int gid = blockIdx.x * 256 + threadIdx.x;   // (b*NC+c)*DI + d
    const int d = gid & (DI - 1);
    const int bc = gid >> 11;                         // b*NC + c
    const int c = bc & (NC - 1);
    const int b = bc >> 5;

    float A[DS], h[DS];
#pragma unroll
    for (int n = 0; n < DS; ++n) {
        A[n] = -__expf(logA[d * DS + n]);
        h[n] = 0.f;
    }
    float dtsum = 0.f;
    const int r0 = b * SEQ + c * CL;
    for (int t = 0; t < CL; ++t) {
        const int r = r0 + t;
        float dtv = dt[(size_t)r * DI + d];
        float xv = xc[(size_t)r * DI + d];
        float bx = dtv * xv;
        dtsum += dtv;
        const float* Bp = xdbl + (size_t)r * XPC + DR;   // wave-uniform
#pragma unroll
        for (int n = 0; n < DS; ++n) {
            float dA = __expf(dtv * A[n]);
            h[n] = dA * h[n] + bx * Bp[n];
        }
    }
#pragma unroll
    for (int n = 0; n < DS; ++n) {
        size_t o = ((size_t)bc * DS + n) * DI + d;
        hend[o] = h[n];
        prodA[o] = __expf(dtsum * A[n]);
    }
}

// Pass 2: sequential combine over the 32 chunks per (b,n,d).
// Rewrites hend in place with the INCOMING state h_in for each chunk.
__global__ __launch_bounds__(256) void scan_pass2(
    float* __restrict__ hend, const float* __restrict__ prodA)
{
    const int gid = blockIdx.x * 256 + threadIdx.x;  // (b*DS+n)*DI + d
    const int d = gid & (DI - 1);
    const int bn = gid >> 11;
    const int n = bn & (DS - 1);
    const int b = bn >> 4;
    float hprev = 0.f;
    for (int c = 0; c < NC; ++c) {
        size_t o = ((size_t)(b * NC + c) * DS + n) * DI + d;
        float tmp = hend[o];
        float P = prodA[o];
        hend[o] = hprev;         // now holds h_in[c]
        hprev = P * hprev + tmp;
    }
}

// Pass 3: re-scan each chunk from h_in, compute y, + x*D, * silu(res) -> yg.
__global__ __launch_bounds__(256) void scan_pass3(
    const float* __restrict__ dt, const float* __restrict__ xc,
    const float* __restrict__ xdbl, const float* __restrict__ res,
    const float* __restrict__ logA, const float* __restrict__ Dp,
    const float* __restrict__ hin, float* __restrict__ yg)
{
    const int gid = blockIdx.x * 256 + threadIdx.x;   // (b*NC+c)*DI + d
    const int d = gid & (DI - 1);
    const int bc = gid >> 11;
    const int c = bc & (NC - 1);
    const int b = bc >> 5;

    float A[DS], h[DS];
#pragma unroll
    for (int n = 0; n < DS; ++n) {
        A[n] = -__expf(logA[d * DS + n]);
        h[n] = hin[((size_t)bc * DS + n) * DI + d];
    }
    const float Dd = Dp[d];
    const int r0 = b * SEQ + c * CL;
    for (int t = 0; t < CL; ++t) {
        const int r = r0 + t;
        float dtv = dt[(size_t)r * DI + d];
        float xv = xc[(size_t)r * DI + d];
        float bx = dtv * xv;
        const float* Bp = xdbl + (size_t)r * XPC + DR;
        const float* Cp = Bp + DS;
        float y = 0.f;
#pragma unroll
        for (int n = 0; n < DS; ++n) {
            float dA = __expf(dtv * A[n]);
            h[n] = dA * h[n] + bx * Bp[n];
            y += h[n] * Cp[n];
        }
        y += xv * Dd;
        float rv = res[(size_t)r * DI + d];
        float sr = rv / (1.f + __expf(-rv));
        yg[(size_t)r * DI + d] = y * sr;
    }
}

extern "C" void kernel_launch(void* const* d_in, const int* in_sizes, int n_in,
                              void* d_out, int out_size, void* d_ws, size_t ws_size,
                              hipStream_t stream) {
    const float* x          = (const float*)d_in[0];
    const float* in_proj_w  = (const float*)d_in[1];
    const float* in_proj_b  = (const float*)d_in[2];
    const float* conv_w     = (const float*)d_in[3];
    const float* conv_b     = (const float*)d_in[4];
    const float* x_proj_w   = (const float*)d_in[5];
    const float* dt_proj_w  = (const float*)d_in[6];
    const float* dt_proj_b  = (const float*)d_in[7];
    const float* log_A      = (const float*)d_in[8];
    const float* Dp         = (const float*)d_in[9];
    const float* out_proj_w = (const float*)d_in[10];
    const float* out_proj_b = (const float*)d_in[11];

    // Workspace layout (floats): 145.5 MB total
    float* ws    = (float*)d_ws;
    float* bufA  = ws;                            // ROWS*DI: x_val raw -> dt
    float* res   = bufA  + (size_t)ROWS * DI;     // ROWS*DI
    float* xc    = res   + (size_t)ROWS * DI;     // ROWS*DI
    float* xdbl  = xc    + (size_t)ROWS * DI;     // ROWS*XPC
    float* hend  = xdbl  + (size_t)ROWS * XPC;    // BATCH*NC*DS*DI (8 MB)
    float* prodA = hend  + (size_t)BATCH * NC * DS * DI;  // 8 MB
    float* yg    = prodA + (size_t)BATCH * NC * DS * DI;  // ROWS*DI (32 MB)

    dim3 blk(256);

    // 1) in_proj split into two N=2048 halves: x_val -> bufA, res -> res
    gemm_f32_bias<<<dim3(DI / GBN, ROWS / GBM), blk, 0, stream>>>(
        x, in_proj_w, in_proj_b, bufA, ROWS, DI, DM, DM, 2 * DI, DI);
    gemm_f32_bias<<<dim3(DI / GBN, ROWS / GBM), blk, 0, stream>>>(
        x, in_proj_w + DI, in_proj_b + DI, res, ROWS, DI, DM, DM, 2 * DI, DI);

    // 2) conv + silu: bufA -> xc
    conv_silu_kernel<<<(ROWS * DI) / 256, blk, 0, stream>>>(bufA, conv_w, conv_b, xc);

    // 3) x_proj: xc -> xdbl
    xproj_kernel<<<ROWS / 8, blk, 0, stream>>>(xc, x_proj_w, xdbl);

    // 4) dt_proj + softplus: xdbl -> bufA (reused as dt)
    dtproj_kernel<<<(ROWS / 8) * (DI / 256), blk, 0, stream>>>(
        xdbl, dt_proj_w, dt_proj_b, bufA);

    // 5) chunked selective scan: dt(bufA), xc, xdbl -> yg
    scan_pass1<<<(BATCH * NC * DI) / 256, blk, 0, stream>>>(
        bufA, xc, xdbl, log_A, hend, prodA);
    scan_pass2<<<(BATCH * DS * DI) / 256, blk, 0, stream>>>(hend, prodA);
    scan_pass3<<<(BATCH * NC * DI) / 256, blk, 0, stream>>>(
        bufA, xc, xdbl, res, log_A, Dp, hend, yg);

    // 6) out_proj: yg(ROWS x DI) @ out_proj_w(DI x DM) + b -> out
    gemm_f32_bias<<<dim3(DM / GBN, ROWS / GBM), blk, 0, stream>>>(
        yg, out_proj_w, out_proj_b, (float*)d_out, ROWS, DM, DI, DI, DM, DM);
}

// Round 5
// 476.671 us; speedup vs baseline: 5.2846x; 2.4214x over previous
//
#include <hip/hip_runtime.h>
#include <hip/hip_bf16.h>

// Problem constants
#define BATCH 2
#define SEQ 2048
#define DM 1024      // d_model
#define DI 2048      // d_inner
#define DS 16        // d_state
#define DR 64        // dt_rank
#define XPC 96       // dt_rank + 2*d_state
#define ROWS 4096    // BATCH*SEQ
#define NC 32        // scan chunks per sequence
#define CL 64        // chunk length = SEQ/NC

typedef __attribute__((ext_vector_type(8))) short bf16x8;
typedef __attribute__((ext_vector_type(4))) float f32x4;
typedef unsigned short ushort_t;

// ---------------- fp32 -> bf16 elementwise convert ----------------
__global__ __launch_bounds__(256) void cvt_f32_bf16(
    const float* __restrict__ in, ushort_t* __restrict__ out)
{
    const size_t i = (size_t)(blockIdx.x * 256 + threadIdx.x) * 4;
    float4 v = *(const float4*)(in + i);
    ushort4 o;
    __hip_bfloat16 b0 = __float2bfloat16(v.x); o.x = *(ushort_t*)&b0;
    __hip_bfloat16 b1 = __float2bfloat16(v.y); o.y = *(ushort_t*)&b1;
    __hip_bfloat16 b2 = __float2bfloat16(v.z); o.z = *(ushort_t*)&b2;
    __hip_bfloat16 b3 = __float2bfloat16(v.w); o.w = *(ushort_t*)&b3;
    *(ushort4*)(out + i) = o;
}

// ---------------- transpose + convert: W[K][N] fp32 -> Wt[N][K] bf16 ----------------
__global__ __launch_bounds__(256) void convt_bf16(
    const float* __restrict__ W, ushort_t* __restrict__ Wt, int K, int N)
{
    __shared__ float t[32][33];
    const int n0 = blockIdx.x * 32, k0 = blockIdx.y * 32;
    const int tx = threadIdx.x & 31, ty = threadIdx.x >> 5;  // 32 x 8
#pragma unroll
    for (int i = 0; i < 32; i += 8)
        t[ty + i][tx] = W[(size_t)(k0 + ty + i) * N + n0 + tx];
    __syncthreads();
#pragma unroll
    for (int i = 0; i < 32; i += 8) {
        __hip_bfloat16 b = __float2bfloat16(t[tx][ty + i]);
        Wt[(size_t)(n0 + ty + i) * K + k0 + tx] = *(ushort_t*)&b;
    }
}

// ---------------- bf16 MFMA GEMM, both operands [row][k] ("B^T") ----------------
// C[M,N] (fp32, ldc=N) = A[M,K]bf16 @ Bt[N,K]bf16^T + bias
// Block: 256 threads = 4 waves in WM x WN grid; each wave FM x FN fragments of 16x16.
template<int BM, int BN, int WM, int WN, int FM, int FN>
__global__ __launch_bounds__(256) void mfma_gemm_bt(
    const ushort_t* __restrict__ A, const ushort_t* __restrict__ Bt,
    const float* __restrict__ bias, float* __restrict__ C,
    int M, int N, int K)
{
    __shared__ ushort_t As[BM * 40];
    __shared__ ushort_t Bs[BN * 40];
    const int tid = threadIdx.x;
    const int wid = tid >> 6, lane = tid & 63;
    const int quad = lane >> 4, l16 = lane & 15;
    const int wr = wid / WN, wc = wid % WN;
    const int bm = blockIdx.y, bn = blockIdx.x;

    f32x4 acc[FM][FN];
#pragma unroll
    for (int m = 0; m < FM; ++m)
#pragma unroll
        for (int n = 0; n < FN; ++n) acc[m][n] = (f32x4){0.f, 0.f, 0.f, 0.f};

    for (int k0 = 0; k0 < K; k0 += 32) {
        // stage A tile: BM x 32 bf16
        for (int i = tid; i < BM * 4; i += 256) {
            int r = i >> 2, kk = (i & 3) << 3;
            *(uint4*)&As[r * 40 + kk] =
                *(const uint4*)&A[(size_t)(bm * BM + r) * K + k0 + kk];
        }
        // stage Bt tile: BN x 32 bf16
        for (int i = tid; i < BN * 4; i += 256) {
            int r = i >> 2, kk = (i & 3) << 3;
            *(uint4*)&Bs[r * 40 + kk] =
                *(const uint4*)&Bt[(size_t)(bn * BN + r) * K + k0 + kk];
        }
        __syncthreads();
        bf16x8 a[FM], b[FN];
#pragma unroll
        for (int m = 0; m < FM; ++m)
            a[m] = *(const bf16x8*)&As[(wr * FM * 16 + m * 16 + l16) * 40 + 8 * quad];
#pragma unroll
        for (int n = 0; n < FN; ++n)
            b[n] = *(const bf16x8*)&Bs[(wc * FN * 16 + n * 16 + l16) * 40 + 8 * quad];
#pragma unroll
        for (int m = 0; m < FM; ++m)
#pragma unroll
            for (int n = 0; n < FN; ++n)
                acc[m][n] = __builtin_amdgcn_mfma_f32_16x16x32_bf16(
                    a[m], b[n], acc[m][n], 0, 0, 0);
        __syncthreads();
    }

#pragma unroll
    for (int m = 0; m < FM; ++m) {
        const int row0 = bm * BM + wr * FM * 16 + m * 16 + quad * 4;
#pragma unroll
        for (int n = 0; n < FN; ++n) {
            const int col = bn * BN + wc * FN * 16 + n * 16 + l16;
            const float bv = bias ? bias[col] : 0.f;
#pragma unroll
            for (int r = 0; r < 4; ++r)
                C[(size_t)(row0 + r) * N + col] = acc[m][n][r] + bv;
        }
    }
}

// ---------------- depthwise causal conv (width 4) + SiLU -> bf16 ----------------
__global__ __launch_bounds__(256) void conv_silu_kernel(
    const float* __restrict__ xv, const float* __restrict__ cw,
    const float* __restrict__ cb, ushort_t* __restrict__ xc)
{
    int idx = blockIdx.x * 256 + threadIdx.x;   // over ROWS*DI
    int r = idx >> 11;          // /DI (2048)
    int d = idx & (DI - 1);
    int t = r & (SEQ - 1);      // position within batch
    float acc = cb[d];
#pragma unroll
    for (int k = 0; k < 4; ++k) {
        int tt = t - 3 + k;
        if (tt >= 0)
            acc += xv[(size_t)(r - 3 + k) * DI + d] * cw[d * 4 + k];
    }
    float sv = acc / (1.f + __expf(-acc));
    __hip_bfloat16 b = __float2bfloat16(sv);
    xc[idx] = *(ushort_t*)&b;
}

// ---------------- dt_proj + softplus: (ROWS x 64) @ (64 x DI) ----------------
__global__ __launch_bounds__(256) void dtproj_kernel(
    const float* __restrict__ xdbl, const float* __restrict__ W,
    const float* __restrict__ bias, float* __restrict__ dt)
{
    __shared__ float rows[8][DR];
    const int rb = (blockIdx.x / 8) * 8;
    const int cb0 = (blockIdx.x % 8) * 256;
    const int tid = threadIdx.x;
    if (tid < 128) {
        int rr = tid / 16, cc = (tid % 16) * 4;
        float4 v = *(const float4*)(xdbl + (size_t)(rb + rr) * XPC + cc);
        *(float4*)&rows[rr][cc] = v;
    }
    __syncthreads();
    const int col = cb0 + tid;
    float acc[8] = {};
    for (int k = 0; k < DR; ++k) {
        float w = W[(size_t)k * DI + col];
#pragma unroll
        for (int rr = 0; rr < 8; ++rr) acc[rr] += rows[rr][k] * w;
    }
    float b = bias[col];
#pragma unroll
    for (int rr = 0; rr < 8; ++rr) {
        float z = acc[rr] + b;
        float sp = (z > 20.f) ? z : log1pf(__expf(z));
        dt[(size_t)(rb + rr) * DI + col] = sp;
    }
}

// ---------------- chunked selective scan ----------------
static __device__ __forceinline__ float bf2f(ushort_t u) {
    __hip_bfloat16 b = *(__hip_bfloat16*)&u;
    return __bfloat162float(b);
}

// Pass 1: per (b,chunk,d) thread, 16 states in registers, local scan from 0.
__global__ __launch_bounds__(256) void scan_pass1(
    const float* __restrict__ dt, const ushort_t* __restrict__ xc,
    const float* __restrict__ xdbl, const float* __restrict__ logA,
    float* __restrict__ hend, float* __restrict__ prodA)
{
    const int gid = blockIdx.x * 256 + threadIdx.x;   // (b*NC+c)*DI + d
    const int d = gid & (DI - 1);
    const int bc = gid >> 11;                         // b*NC + c
    const int c = bc & (NC - 1);
    const int b = bc >> 5;

    float A[DS], h[DS];
#pragma unroll
    for (int n = 0; n < DS; ++n) {
        A[n] = -__expf(logA[d * DS + n]);
        h[n] = 0.f;
    }
    float dtsum = 0.f;
    const int r0 = b * SEQ + c * CL;
    for (int t = 0; t < CL; ++t) {
        const int r = r0 + t;
        float dtv = dt[(size_t)r * DI + d];
        float xv = bf2f(xc[(size_t)r * DI + d]);
        float bx = dtv * xv;
        dtsum += dtv;
        const float* Bp = xdbl + (size_t)r * XPC + DR;   // wave-uniform
#pragma unroll
        for (int n = 0; n < DS; ++n) {
            float dA = __expf(dtv * A[n]);
            h[n] = dA * h[n] + bx * Bp[n];
        }
    }
#pragma unroll
    for (int n = 0; n < DS; ++n) {
        size_t o = ((size_t)bc * DS + n) * DI + d;
        hend[o] = h[n];
        prodA[o] = __expf(dtsum * A[n]);
    }
}

// Pass 2: sequential combine over the 32 chunks per (b,n,d); hend -> h_in in place.
__global__ __launch_bounds__(256) void scan_pass2(
    float* __restrict__ hend, const float* __restrict__ prodA)
{
    const int gid = blockIdx.x * 256 + threadIdx.x;  // (b*DS+n)*DI + d
    const int d = gid & (DI - 1);
    const int bn = gid >> 11;
    const int n = bn & (DS - 1);
    const int b = bn >> 4;
    float hprev = 0.f;
    for (int c = 0; c < NC; ++c) {
        size_t o = ((size_t)(b * NC + c) * DS + n) * DI + d;
        float tmp = hend[o];
        float P = prodA[o];
        hend[o] = hprev;         // now holds h_in[c]
        hprev = P * hprev + tmp;
    }
}

// Pass 3: re-scan each chunk from h_in; y, +x*D, *silu(res) -> yg (bf16).
__global__ __launch_bounds__(256) void scan_pass3(
    const float* __restrict__ dt, const ushort_t* __restrict__ xc,
    const float* __restrict__ xdbl, const float* __restrict__ res,
    const float* __restrict__ logA, const float* __restrict__ Dp,
    const float* __restrict__ hin, ushort_t* __restrict__ yg)
{
    const int gid = blockIdx.x * 256 + threadIdx.x;   // (b*NC+c)*DI + d
    const int d = gid & (DI - 1);
    const int bc = gid >> 11;
    const int c = bc & (NC - 1);
    const int b = bc >> 5;

    float A[DS], h[DS];
#pragma unroll
    for (int n = 0; n < DS; ++n) {
        A[n] = -__expf(logA[d * DS + n]);
        h[n] = hin[((size_t)bc * DS + n) * DI + d];
    }
    const float Dd = Dp[d];
    const int r0 = b * SEQ + c * CL;
    for (int t = 0; t < CL; ++t) {
        const int r = r0 + t;
        float dtv = dt[(size_t)r * DI + d];
        float xv = bf2f(xc[(size_t)r * DI + d]);
        float bx = dtv * xv;
        const float* Bp = xdbl + (size_t)r * XPC + DR;
        const float* Cp = Bp + DS;
        float y = 0.f;
#pragma unroll
        for (int n = 0; n < DS; ++n) {
            float dA = __expf(dtv * A[n]);
            h[n] = dA * h[n] + bx * Bp[n];
            y += h[n] * Cp[n];
        }
        y += xv * Dd;
        float rv = res[(size_t)r * DI + d];
        float sr = rv / (1.f + __expf(-rv));
        __hip_bfloat16 o = __float2bfloat16(y * sr);
        yg[(size_t)r * DI + d] = *(ushort_t*)&o;
    }
}

extern "C" void kernel_launch(void* const* d_in, const int* in_sizes, int n_in,
                              void* d_out, int out_size, void* d_ws, size_t ws_size,
                              hipStream_t stream) {
    const float* x          = (const float*)d_in[0];
    const float* in_proj_w  = (const float*)d_in[1];
    const float* in_proj_b  = (const float*)d_in[2];
    const float* conv_w     = (const float*)d_in[3];
    const float* conv_b     = (const float*)d_in[4];
    const float* x_proj_w   = (const float*)d_in[5];
    const float* dt_proj_w  = (const float*)d_in[6];
    const float* dt_proj_b  = (const float*)d_in[7];
    const float* log_A      = (const float*)d_in[8];
    const float* Dp         = (const float*)d_in[9];
    const float* out_proj_w = (const float*)d_in[10];
    const float* out_proj_b = (const float*)d_in[11];

    // Workspace layout (~134 MB)
    float* ws    = (float*)d_ws;
    float* bufA  = ws;                            // ROWS*DI fp32: x_val -> dt
    float* res   = bufA  + (size_t)ROWS * DI;     // ROWS*DI fp32
    float* xdbl  = res   + (size_t)ROWS * DI;     // ROWS*XPC fp32
    float* hend  = xdbl  + (size_t)ROWS * XPC;    // BATCH*NC*DS*DI fp32 (8 MB)
    float* prodA = hend  + (size_t)BATCH * NC * DS * DI;  // 8 MB
    ushort_t* xc_bf   = (ushort_t*)(prodA + (size_t)BATCH * NC * DS * DI); // ROWS*DI bf16
    ushort_t* yg_bf   = xc_bf  + (size_t)ROWS * DI;       // ROWS*DI bf16
    ushort_t* x_bf    = yg_bf  + (size_t)ROWS * DI;       // ROWS*DM bf16
    ushort_t* wt_in   = x_bf   + (size_t)ROWS * DM;       // [2*DI][DM] bf16
    ushort_t* wt_out  = wt_in  + (size_t)2 * DI * DM;     // [DM][DI] bf16
    ushort_t* wt_xp   = wt_out + (size_t)DM * DI;         // [XPC][DI] bf16

    dim3 blk(256);

    // 0) converts (once per launch)
    cvt_f32_bf16<<<(ROWS * DM / 4) / 256, blk, 0, stream>>>(x, x_bf);
    convt_bf16<<<dim3(2 * DI / 32, DM / 32), blk, 0, stream>>>(in_proj_w, wt_in, DM, 2 * DI);
    convt_bf16<<<dim3(DM / 32, DI / 32), blk, 0, stream>>>(out_proj_w, wt_out, DI, DM);
    convt_bf16<<<dim3(XPC / 32, DI / 32), blk, 0, stream>>>(x_proj_w, wt_xp, DI, XPC);

    // 1) in_proj (two N=2048 halves): x_val -> bufA, res -> res
    mfma_gemm_bt<128, 128, 2, 2, 4, 4><<<dim3(DI / 128, ROWS / 128), blk, 0, stream>>>(
        x_bf, wt_in, in_proj_b, bufA, ROWS, DI, DM);
    mfma_gemm_bt<128, 128, 2, 2, 4, 4><<<dim3(DI / 128, ROWS / 128), blk, 0, stream>>>(
        x_bf, wt_in + (size_t)DI * DM, in_proj_b + DI, res, ROWS, DI, DM);

    // 2) conv + silu: bufA -> xc (bf16)
    conv_silu_kernel<<<(ROWS * DI) / 256, blk, 0, stream>>>(bufA, conv_w, conv_b, xc_bf);

    // 3) x_proj: xc_bf @ wt_xp^T -> xdbl (fp32)
    mfma_gemm_bt<64, 96, 4, 1, 1, 6><<<dim3(1, ROWS / 64), blk, 0, stream>>>(
        xc_bf, wt_xp, nullptr, xdbl, ROWS, XPC, DI);

    // 4) dt_proj + softplus: xdbl -> bufA (reused as dt)
    dtproj_kernel<<<(ROWS / 8) * (DI / 256), blk, 0, stream>>>(
        xdbl, dt_proj_w, dt_proj_b, bufA);

    // 5) chunked selective scan
    scan_pass1<<<(BATCH * NC * DI) / 256, blk, 0, stream>>>(
        bufA, xc_bf, xdbl, log_A, hend, prodA);
    scan_pass2<<<(BATCH * DS * DI) / 256, blk, 0, stream>>>(hend, prodA);
    scan_pass3<<<(BATCH * NC * DI) / 256, blk, 0, stream>>>(
        bufA, xc_bf, xdbl, res, log_A, Dp, hend, yg_bf);

    // 6) out_proj: yg_bf @ wt_out^T + b -> out
    mfma_gemm_bt<128, 128, 2, 2, 4, 4><<<dim3(DM / 128, ROWS / 128), blk, 0, stream>>>(
        yg_bf, wt_out, out_proj_b, (float*)d_out, ROWS, DM, DI);
}

// Round 6
// 393.434 us; speedup vs baseline: 6.4027x; 1.2116x over previous
//
#include <hip/hip_runtime.h>
#include <hip/hip_bf16.h>

// Problem constants
#define BATCH 2
#define SEQ 2048
#define DM 1024      // d_model
#define DI 2048      // d_inner
#define DS 16        // d_state
#define DR 64        // dt_rank
#define XPC 96       // dt_rank + 2*d_state
#define ROWS 4096    // BATCH*SEQ
#define NC 32        // scan chunks per sequence
#define CL 64        // chunk length = SEQ/NC
#define XRLD 4096    // ld of fused in_proj output (x_val | res)

typedef __attribute__((ext_vector_type(8))) short bf16x8;
typedef __attribute__((ext_vector_type(4))) float f32x4;
typedef unsigned short ushort_t;
typedef unsigned int u32;

#define GLD_LDS16(g, l) \
    __builtin_amdgcn_global_load_lds((const __attribute__((address_space(1))) u32*)(g), \
                                     (__attribute__((address_space(3))) u32*)(l), 16, 0, 0)

// ---------------- fp32 -> bf16 elementwise convert ----------------
__global__ __launch_bounds__(256) void cvt_f32_bf16(
    const float* __restrict__ in, ushort_t* __restrict__ out)
{
    const size_t i = (size_t)(blockIdx.x * 256 + threadIdx.x) * 4;
    float4 v = *(const float4*)(in + i);
    ushort4 o;
    __hip_bfloat16 b0 = __float2bfloat16(v.x); o.x = *(ushort_t*)&b0;
    __hip_bfloat16 b1 = __float2bfloat16(v.y); o.y = *(ushort_t*)&b1;
    __hip_bfloat16 b2 = __float2bfloat16(v.z); o.z = *(ushort_t*)&b2;
    __hip_bfloat16 b3 = __float2bfloat16(v.w); o.w = *(ushort_t*)&b3;
    *(ushort4*)(out + i) = o;
}

// ---------------- transpose + convert: W[K][N] fp32 -> Wt[N][K] bf16 ----------------
__global__ __launch_bounds__(256) void convt_bf16(
    const float* __restrict__ W, ushort_t* __restrict__ Wt, int K, int N)
{
    __shared__ float t[32][33];
    const int n0 = blockIdx.x * 32, k0 = blockIdx.y * 32;
    const int tx = threadIdx.x & 31, ty = threadIdx.x >> 5;  // 32 x 8
#pragma unroll
    for (int i = 0; i < 32; i += 8)
        t[ty + i][tx] = W[(size_t)(k0 + ty + i) * N + n0 + tx];
    __syncthreads();
#pragma unroll
    for (int i = 0; i < 32; i += 8) {
        __hip_bfloat16 b = __float2bfloat16(t[tx][ty + i]);
        Wt[(size_t)(n0 + ty + i) * K + k0 + tx] = *(ushort_t*)&b;
    }
}

// ---------------- m97-structure 128x128 bf16 MFMA GEMM ("B^T" operands) ----------------
// C[bm*128.., bn*128..] = A[M,K]bf16 @ Bt[N,K]bf16^T + bias; C fp32 with ldc.
// 4 waves (2x2), each wave 64x64 = 4x4 frags; BK=32; global_load_lds staging (linear LDS).
__global__ __launch_bounds__(256) void gemm128_bt(
    const ushort_t* __restrict__ A, const ushort_t* __restrict__ Bt,
    const float* __restrict__ bias, float* __restrict__ C,
    int K, int ldc)
{
    __shared__ ushort_t As[128 * 32];
    __shared__ ushort_t Bs[128 * 32];
    const int tid = threadIdx.x;
    const int lane = tid & 63, wid = tid >> 6;
    const int quad = lane >> 4, l16 = lane & 15;
    const int wr = wid >> 1, wc = wid & 1;
    const int bm = blockIdx.y, bn = blockIdx.x;

    // staging: chunk c (16B) covers row c/4, k-eighth (c%4)*8; thread does c=tid, c=tid+256
    const int sr = tid >> 2, sk = (tid & 3) << 3;
    const ushort_t* Ag0 = A + (size_t)(bm * 128 + sr) * K + sk;
    const ushort_t* Ag1 = A + (size_t)(bm * 128 + 64 + sr) * K + sk;
    const ushort_t* Bg0 = Bt + (size_t)(bn * 128 + sr) * K + sk;
    const ushort_t* Bg1 = Bt + (size_t)(bn * 128 + 64 + sr) * K + sk;
    ushort_t* As0 = As + tid * 8;
    ushort_t* As1 = As + (tid + 256) * 8;
    ushort_t* Bs0 = Bs + tid * 8;
    ushort_t* Bs1 = Bs + (tid + 256) * 8;

    f32x4 acc[4][4];
#pragma unroll
    for (int m = 0; m < 4; ++m)
#pragma unroll
        for (int n = 0; n < 4; ++n) acc[m][n] = (f32x4){0.f, 0.f, 0.f, 0.f};

    for (int k0 = 0; k0 < K; k0 += 32) {
        GLD_LDS16(Ag0 + k0, As0);
        GLD_LDS16(Ag1 + k0, As1);
        GLD_LDS16(Bg0 + k0, Bs0);
        GLD_LDS16(Bg1 + k0, Bs1);
        __syncthreads();
        bf16x8 a[4], b[4];
#pragma unroll
        for (int m = 0; m < 4; ++m)
            a[m] = *(const bf16x8*)&As[(wr * 64 + m * 16 + l16) * 32 + 8 * quad];
#pragma unroll
        for (int n = 0; n < 4; ++n)
            b[n] = *(const bf16x8*)&Bs[(wc * 64 + n * 16 + l16) * 32 + 8 * quad];
#pragma unroll
        for (int m = 0; m < 4; ++m)
#pragma unroll
            for (int n = 0; n < 4; ++n)
                acc[m][n] = __builtin_amdgcn_mfma_f32_16x16x32_bf16(
                    a[m], b[n], acc[m][n], 0, 0, 0);
        __syncthreads();
    }

#pragma unroll
    for (int m = 0; m < 4; ++m) {
        const int row0 = bm * 128 + wr * 64 + m * 16 + quad * 4;
#pragma unroll
        for (int n = 0; n < 4; ++n) {
            const int col = bn * 128 + wc * 64 + n * 16 + l16;
            const float bv = bias ? bias[col] : 0.f;
#pragma unroll
            for (int r = 0; r < 4; ++r)
                C[(size_t)(row0 + r) * ldc + col] = acc[m][n][r] + bv;
        }
    }
}

// ---------------- skinny x_proj GEMM (64x96 tile), padded-LDS path ----------------
template<int BM, int BN, int WM, int WN, int FM, int FN>
__global__ __launch_bounds__(256) void mfma_gemm_bt(
    const ushort_t* __restrict__ A, const ushort_t* __restrict__ Bt,
    const float* __restrict__ bias, float* __restrict__ C,
    int M, int N, int K)
{
    __shared__ ushort_t As[BM * 40];
    __shared__ ushort_t Bs[BN * 40];
    const int tid = threadIdx.x;
    const int wid = tid >> 6, lane = tid & 63;
    const int quad = lane >> 4, l16 = lane & 15;
    const int wr = wid / WN, wc = wid % WN;
    const int bm = blockIdx.y, bn = blockIdx.x;

    f32x4 acc[FM][FN];
#pragma unroll
    for (int m = 0; m < FM; ++m)
#pragma unroll
        for (int n = 0; n < FN; ++n) acc[m][n] = (f32x4){0.f, 0.f, 0.f, 0.f};

    for (int k0 = 0; k0 < K; k0 += 32) {
        for (int i = tid; i < BM * 4; i += 256) {
            int r = i >> 2, kk = (i & 3) << 3;
            *(uint4*)&As[r * 40 + kk] =
                *(const uint4*)&A[(size_t)(bm * BM + r) * K + k0 + kk];
        }
        for (int i = tid; i < BN * 4; i += 256) {
            int r = i >> 2, kk = (i & 3) << 3;
            *(uint4*)&Bs[r * 40 + kk] =
                *(const uint4*)&Bt[(size_t)(bn * BN + r) * K + k0 + kk];
        }
        __syncthreads();
        bf16x8 a[FM], b[FN];
#pragma unroll
        for (int m = 0; m < FM; ++m)
            a[m] = *(const bf16x8*)&As[(wr * FM * 16 + m * 16 + l16) * 40 + 8 * quad];
#pragma unroll
        for (int n = 0; n < FN; ++n)
            b[n] = *(const bf16x8*)&Bs[(wc * FN * 16 + n * 16 + l16) * 40 + 8 * quad];
#pragma unroll
        for (int m = 0; m < FM; ++m)
#pragma unroll
            for (int n = 0; n < FN; ++n)
                acc[m][n] = __builtin_amdgcn_mfma_f32_16x16x32_bf16(
                    a[m], b[n], acc[m][n], 0, 0, 0);
        __syncthreads();
    }

#pragma unroll
    for (int m = 0; m < FM; ++m) {
        const int row0 = bm * BM + wr * FM * 16 + m * 16 + quad * 4;
#pragma unroll
        for (int n = 0; n < FN; ++n) {
            const int col = bn * BN + wc * FN * 16 + n * 16 + l16;
            const float bv = bias ? bias[col] : 0.f;
#pragma unroll
            for (int r = 0; r < 4; ++r)
                C[(size_t)(row0 + r) * N + col] = acc[m][n][r] + bv;
        }
    }
}

// ---------------- depthwise causal conv (width 4) + SiLU -> bf16 ----------------
// x_val lives in xr[:, 0:DI] with ld XRLD
__global__ __launch_bounds__(256) void conv_silu_kernel(
    const float* __restrict__ xr, const float* __restrict__ cw,
    const float* __restrict__ cb, ushort_t* __restrict__ xc)
{
    int idx = blockIdx.x * 256 + threadIdx.x;   // over ROWS*DI
    int r = idx >> 11;          // /DI (2048)
    int d = idx & (DI - 1);
    int t = r & (SEQ - 1);      // position within batch
    float acc = cb[d];
#pragma unroll
    for (int k = 0; k < 4; ++k) {
        int tt = t - 3 + k;
        if (tt >= 0)
            acc += xr[(size_t)(r - 3 + k) * XRLD + d] * cw[d * 4 + k];
    }
    float sv = acc / (1.f + __expf(-acc));
    __hip_bfloat16 b = __float2bfloat16(sv);
    xc[idx] = *(ushort_t*)&b;
}

// ---------------- dt_proj + softplus -> dt (stored in xr[:,0:DI], ld XRLD) ----------------
__global__ __launch_bounds__(256) void dtproj_kernel(
    const float* __restrict__ xdbl, const float* __restrict__ W,
    const float* __restrict__ bias, float* __restrict__ dt)
{
    __shared__ float rows[8][DR];
    const int rb = (blockIdx.x / 8) * 8;
    const int cb0 = (blockIdx.x % 8) * 256;
    const int tid = threadIdx.x;
    if (tid < 128) {
        int rr = tid / 16, cc = (tid % 16) * 4;
        float4 v = *(const float4*)(xdbl + (size_t)(rb + rr) * XPC + cc);
        *(float4*)&rows[rr][cc] = v;
    }
    __syncthreads();
    const int col = cb0 + tid;
    float acc[8] = {};
    for (int k = 0; k < DR; ++k) {
        float w = W[(size_t)k * DI + col];
#pragma unroll
        for (int rr = 0; rr < 8; ++rr) acc[rr] += rows[rr][k] * w;
    }
    float b = bias[col];
#pragma unroll
    for (int rr = 0; rr < 8; ++rr) {
        float z = acc[rr] + b;
        float sp = (z > 20.f) ? z : log1pf(__expf(z));
        dt[(size_t)(rb + rr) * XRLD + col] = sp;
    }
}

// ---------------- chunked selective scan ----------------
static __device__ __forceinline__ float bf2f(ushort_t u) {
    __hip_bfloat16 b = *(__hip_bfloat16*)&u;
    return __bfloat162float(b);
}

// Pass 1: per (b,chunk,d) thread, 16 states in registers, local scan from 0.
__global__ __launch_bounds__(256) void scan_pass1(
    const float* __restrict__ dt, const ushort_t* __restrict__ xc,
    const float* __restrict__ xdbl, const float* __restrict__ logA,
    float* __restrict__ hend, float* __restrict__ prodA)
{
    const int gid = blockIdx.x * 256 + threadIdx.x;   // (b*NC+c)*DI + d
    const int d = gid & (DI - 1);
    const int bc = gid >> 11;                         // b*NC + c
    const int c = bc & (NC - 1);
    const int b = bc >> 5;

    float A[DS], h[DS];
#pragma unroll
    for (int n = 0; n < DS; ++n) {
        A[n] = -__expf(logA[d * DS + n]);
        h[n] = 0.f;
    }
    float dtsum = 0.f;
    const int r0 = b * SEQ + c * CL;
    for (int t = 0; t < CL; ++t) {
        const int r = r0 + t;
        float dtv = dt[(size_t)r * XRLD + d];
        float xv = bf2f(xc[(size_t)r * DI + d]);
        float bx = dtv * xv;
        dtsum += dtv;
        const float* Bp = xdbl + (size_t)r * XPC + DR;   // wave-uniform
#pragma unroll
        for (int n = 0; n < DS; ++n) {
            float dA = __expf(dtv * A[n]);
            h[n] = dA * h[n] + bx * Bp[n];
        }
    }
#pragma unroll
    for (int n = 0; n < DS; ++n) {
        size_t o = ((size_t)bc * DS + n) * DI + d;
        hend[o] = h[n];
        prodA[o] = __expf(dtsum * A[n]);
    }
}

// Pass 2: sequential combine over the 32 chunks per (b,n,d); hend -> h_in in place.
__global__ __launch_bounds__(256) void scan_pass2(
    float* __restrict__ hend, const float* __restrict__ prodA)
{
    const int gid = blockIdx.x * 256 + threadIdx.x;  // (b*DS+n)*DI + d
    const int d = gid & (DI - 1);
    const int bn = gid >> 11;
    const int n = bn & (DS - 1);
    const int b = bn >> 4;
    float hprev = 0.f;
    for (int c = 0; c < NC; ++c) {
        size_t o = ((size_t)(b * NC + c) * DS + n) * DI + d;
        float tmp = hend[o];
        float P = prodA[o];
        hend[o] = hprev;         // now holds h_in[c]
        hprev = P * hprev + tmp;
    }
}

// Pass 3: re-scan each chunk from h_in; y, +x*D, *silu(res) -> yg (bf16).
__global__ __launch_bounds__(256) void scan_pass3(
    const float* __restrict__ dt, const ushort_t* __restrict__ xc,
    const float* __restrict__ xdbl, const float* __restrict__ res,
    const float* __restrict__ logA, const float* __restrict__ Dp,
    const float* __restrict__ hin, ushort_t* __restrict__ yg)
{
    const int gid = blockIdx.x * 256 + threadIdx.x;   // (b*NC+c)*DI + d
    const int d = gid & (DI - 1);
    const int bc = gid >> 11;
    const int c = bc & (NC - 1);
    const int b = bc >> 5;

    float A[DS], h[DS];
#pragma unroll
    for (int n = 0; n < DS; ++n) {
        A[n] = -__expf(logA[d * DS + n]);
        h[n] = hin[((size_t)bc * DS + n) * DI + d];
    }
    const float Dd = Dp[d];
    const int r0 = b * SEQ + c * CL;
    for (int t = 0; t < CL; ++t) {
        const int r = r0 + t;
        float dtv = dt[(size_t)r * XRLD + d];
        float xv = bf2f(xc[(size_t)r * DI + d]);
        float bx = dtv * xv;
        const float* Bp = xdbl + (size_t)r * XPC + DR;
        const float* Cp = Bp + DS;
        float y = 0.f;
#pragma unroll
        for (int n = 0; n < DS; ++n) {
            float dA = __expf(dtv * A[n]);
            h[n] = dA * h[n] + bx * Bp[n];
            y += h[n] * Cp[n];
        }
        y += xv * Dd;
        float rv = res[(size_t)r * XRLD + d];
        float sr = rv / (1.f + __expf(-rv));
        __hip_bfloat16 o = __float2bfloat16(y * sr);
        yg[(size_t)r * DI + d] = *(ushort_t*)&o;
    }
}

extern "C" void kernel_launch(void* const* d_in, const int* in_sizes, int n_in,
                              void* d_out, int out_size, void* d_ws, size_t ws_size,
                              hipStream_t stream) {
    const float* x          = (const float*)d_in[0];
    const float* in_proj_w  = (const float*)d_in[1];
    const float* in_proj_b  = (const float*)d_in[2];
    const float* conv_w     = (const float*)d_in[3];
    const float* conv_b     = (const float*)d_in[4];
    const float* x_proj_w   = (const float*)d_in[5];
    const float* dt_proj_w  = (const float*)d_in[6];
    const float* dt_proj_b  = (const float*)d_in[7];
    const float* log_A      = (const float*)d_in[8];
    const float* Dp         = (const float*)d_in[9];
    const float* out_proj_w = (const float*)d_in[10];
    const float* out_proj_b = (const float*)d_in[11];

    // Workspace layout (~134 MB)
    float* ws    = (float*)d_ws;
    float* xr    = ws;                            // ROWS*XRLD fp32: [x_val|res]; x_val cols reused for dt
    float* xdbl  = xr    + (size_t)ROWS * XRLD;   // ROWS*XPC fp32
    float* hend  = xdbl  + (size_t)ROWS * XPC;    // BATCH*NC*DS*DI fp32 (8 MB)
    float* prodA = hend  + (size_t)BATCH * NC * DS * DI;  // 8 MB
    ushort_t* xc_bf   = (ushort_t*)(prodA + (size_t)BATCH * NC * DS * DI); // ROWS*DI bf16
    ushort_t* yg_bf   = xc_bf  + (size_t)ROWS * DI;       // ROWS*DI bf16
    ushort_t* x_bf    = yg_bf  + (size_t)ROWS * DI;       // ROWS*DM bf16
    ushort_t* wt_in   = x_bf   + (size_t)ROWS * DM;       // [2*DI][DM] bf16
    ushort_t* wt_out  = wt_in  + (size_t)2 * DI * DM;     // [DM][DI] bf16
    ushort_t* wt_xp   = wt_out + (size_t)DM * DI;         // [XPC][DI] bf16

    dim3 blk(256);

    // 0) converts (once per launch)
    cvt_f32_bf16<<<(ROWS * DM / 4) / 256, blk, 0, stream>>>(x, x_bf);
    convt_bf16<<<dim3(2 * DI / 32, DM / 32), blk, 0, stream>>>(in_proj_w, wt_in, DM, 2 * DI);
    convt_bf16<<<dim3(DM / 32, DI / 32), blk, 0, stream>>>(out_proj_w, wt_out, DI, DM);
    convt_bf16<<<dim3(XPC / 32, DI / 32), blk, 0, stream>>>(x_proj_w, wt_xp, DI, XPC);

    // 1) in_proj fused (N=4096): x_bf @ wt_in^T + b -> xr
    gemm128_bt<<<dim3(XRLD / 128, ROWS / 128), blk, 0, stream>>>(
        x_bf, wt_in, in_proj_b, xr, DM, XRLD);

    // 2) conv + silu: xr[:,0:DI] -> xc (bf16)
    conv_silu_kernel<<<(ROWS * DI) / 256, blk, 0, stream>>>(xr, conv_w, conv_b, xc_bf);

    // 3) x_proj: xc_bf @ wt_xp^T -> xdbl (fp32)
    mfma_gemm_bt<64, 96, 4, 1, 1, 6><<<dim3(1, ROWS / 64), blk, 0, stream>>>(
        xc_bf, wt_xp, nullptr, xdbl, ROWS, XPC, DI);

    // 4) dt_proj + softplus: xdbl -> dt (xr cols 0..DI, x_val raw now dead)
    dtproj_kernel<<<(ROWS / 8) * (DI / 256), blk, 0, stream>>>(
        xdbl, dt_proj_w, dt_proj_b, xr);

    // 5) chunked selective scan (dt & res both in xr)
    scan_pass1<<<(BATCH * NC * DI) / 256, blk, 0, stream>>>(
        xr, xc_bf, xdbl, log_A, hend, prodA);
    scan_pass2<<<(BATCH * DS * DI) / 256, blk, 0, stream>>>(hend, prodA);
    scan_pass3<<<(BATCH * NC * DI) / 256, blk, 0, stream>>>(
        xr, xc_bf, xdbl, xr + DI, log_A, Dp, hend, yg_bf);

    // 6) out_proj: yg_bf @ wt_out^T + b -> out
    gemm128_bt<<<dim3(DM / 128, ROWS / 128), blk, 0, stream>>>(
        yg_bf, wt_out, out_proj_b, (float*)d_out, DI, DM);
}

// Round 7
// 353.000 us; speedup vs baseline: 7.1361x; 1.1145x over previous
//
#include <hip/hip_runtime.h>
#include <hip/hip_bf16.h>

// Problem constants
#define BATCH 2
#define SEQ 2048
#define DM 1024      // d_model
#define DI 2048      // d_inner
#define DS 16        // d_state
#define DR 64        // dt_rank
#define XPC 96       // dt_rank + 2*d_state
#define ROWS 4096    // BATCH*SEQ
#define NC 32        // scan chunks per sequence
#define CL 64        // chunk length = SEQ/NC
#define XRLD 4096    // ld of fused in_proj output (x_val | res), bf16

typedef __attribute__((ext_vector_type(8))) short bf16x8;
typedef __attribute__((ext_vector_type(4))) float f32x4;
typedef unsigned short ushort_t;
typedef unsigned int u32;

#define GLD_LDS16(g, l) \
    __builtin_amdgcn_global_load_lds((const __attribute__((address_space(1))) u32*)(g), \
                                     (__attribute__((address_space(3))) u32*)(l), 16, 0, 0)

static __device__ __forceinline__ float bf2f(ushort_t u) {
    __hip_bfloat16 b = *(__hip_bfloat16*)&u;
    return __bfloat162float(b);
}
static __device__ __forceinline__ ushort_t f2bf(float f) {
    __hip_bfloat16 b = __float2bfloat16(f);
    return *(ushort_t*)&b;
}

// ---------------- fp32 -> bf16 elementwise convert ----------------
__global__ __launch_bounds__(256) void cvt_f32_bf16(
    const float* __restrict__ in, ushort_t* __restrict__ out)
{
    const size_t i = (size_t)(blockIdx.x * 256 + threadIdx.x) * 4;
    float4 v = *(const float4*)(in + i);
    ushort4 o;
    o.x = f2bf(v.x); o.y = f2bf(v.y); o.z = f2bf(v.z); o.w = f2bf(v.w);
    *(ushort4*)(out + i) = o;
}

// ---------------- transpose + convert: W[K][N] fp32 -> Wt[N][K] bf16 ----------------
__global__ __launch_bounds__(256) void convt_bf16(
    const float* __restrict__ W, ushort_t* __restrict__ Wt, int K, int N)
{
    __shared__ float t[32][33];
    const int n0 = blockIdx.x * 32, k0 = blockIdx.y * 32;
    const int tx = threadIdx.x & 31, ty = threadIdx.x >> 5;  // 32 x 8
#pragma unroll
    for (int i = 0; i < 32; i += 8)
        t[ty + i][tx] = W[(size_t)(k0 + ty + i) * N + n0 + tx];
    __syncthreads();
#pragma unroll
    for (int i = 0; i < 32; i += 8)
        Wt[(size_t)(n0 + ty + i) * K + k0 + tx] = f2bf(t[tx][ty + i]);
}

// ---------------- m97-structure 128x128 bf16 MFMA GEMM ("B^T" operands) ----------------
// C = A[M,K]bf16 @ Bt[N,K]bf16^T + bias; output fp32 or bf16 (BF16OUT).
// 4 waves (2x2), each wave 64x64 = 4x4 frags; BK=32; global_load_lds staging (linear LDS).
template<bool BF16OUT, typename OutT>
__global__ __launch_bounds__(256) void gemm128_bt(
    const ushort_t* __restrict__ A, const ushort_t* __restrict__ Bt,
    const float* __restrict__ bias, OutT* __restrict__ C,
    int K, int ldc)
{
    __shared__ ushort_t As[128 * 32];
    __shared__ ushort_t Bs[128 * 32];
    const int tid = threadIdx.x;
    const int lane = tid & 63, wid = tid >> 6;
    const int quad = lane >> 4, l16 = lane & 15;
    const int wr = wid >> 1, wc = wid & 1;
    const int bm = blockIdx.y, bn = blockIdx.x;

    const int sr = tid >> 2, sk = (tid & 3) << 3;
    const ushort_t* Ag0 = A + (size_t)(bm * 128 + sr) * K + sk;
    const ushort_t* Ag1 = A + (size_t)(bm * 128 + 64 + sr) * K + sk;
    const ushort_t* Bg0 = Bt + (size_t)(bn * 128 + sr) * K + sk;
    const ushort_t* Bg1 = Bt + (size_t)(bn * 128 + 64 + sr) * K + sk;
    ushort_t* As0 = As + tid * 8;
    ushort_t* As1 = As + (tid + 256) * 8;
    ushort_t* Bs0 = Bs + tid * 8;
    ushort_t* Bs1 = Bs + (tid + 256) * 8;

    f32x4 acc[4][4];
#pragma unroll
    for (int m = 0; m < 4; ++m)
#pragma unroll
        for (int n = 0; n < 4; ++n) acc[m][n] = (f32x4){0.f, 0.f, 0.f, 0.f};

    for (int k0 = 0; k0 < K; k0 += 32) {
        GLD_LDS16(Ag0 + k0, As0);
        GLD_LDS16(Ag1 + k0, As1);
        GLD_LDS16(Bg0 + k0, Bs0);
        GLD_LDS16(Bg1 + k0, Bs1);
        __syncthreads();
        bf16x8 a[4], b[4];
#pragma unroll
        for (int m = 0; m < 4; ++m)
            a[m] = *(const bf16x8*)&As[(wr * 64 + m * 16 + l16) * 32 + 8 * quad];
#pragma unroll
        for (int n = 0; n < 4; ++n)
            b[n] = *(const bf16x8*)&Bs[(wc * 64 + n * 16 + l16) * 32 + 8 * quad];
#pragma unroll
        for (int m = 0; m < 4; ++m)
#pragma unroll
            for (int n = 0; n < 4; ++n)
                acc[m][n] = __builtin_amdgcn_mfma_f32_16x16x32_bf16(
                    a[m], b[n], acc[m][n], 0, 0, 0);
        __syncthreads();
    }

#pragma unroll
    for (int m = 0; m < 4; ++m) {
        const int row0 = bm * 128 + wr * 64 + m * 16 + quad * 4;
#pragma unroll
        for (int n = 0; n < 4; ++n) {
            const int col = bn * 128 + wc * 64 + n * 16 + l16;
            const float bv = bias ? bias[col] : 0.f;
#pragma unroll
            for (int r = 0; r < 4; ++r) {
                float v = acc[m][n][r] + bv;
                if constexpr (BF16OUT)
                    ((ushort_t*)C)[(size_t)(row0 + r) * ldc + col] = f2bf(v);
                else
                    ((float*)C)[(size_t)(row0 + r) * ldc + col] = v;
            }
        }
    }
}

// ---------------- skinny x_proj GEMM (64x96 tile), padded-LDS path ----------------
template<int BM, int BN, int WM, int WN, int FM, int FN>
__global__ __launch_bounds__(256) void mfma_gemm_bt(
    const ushort_t* __restrict__ A, const ushort_t* __restrict__ Bt,
    const float* __restrict__ bias, float* __restrict__ C,
    int M, int N, int K)
{
    __shared__ ushort_t As[BM * 40];
    __shared__ ushort_t Bs[BN * 40];
    const int tid = threadIdx.x;
    const int wid = tid >> 6, lane = tid & 63;
    const int quad = lane >> 4, l16 = lane & 15;
    const int wr = wid / WN, wc = wid % WN;
    const int bm = blockIdx.y, bn = blockIdx.x;

    f32x4 acc[FM][FN];
#pragma unroll
    for (int m = 0; m < FM; ++m)
#pragma unroll
        for (int n = 0; n < FN; ++n) acc[m][n] = (f32x4){0.f, 0.f, 0.f, 0.f};

    for (int k0 = 0; k0 < K; k0 += 32) {
        for (int i = tid; i < BM * 4; i += 256) {
            int r = i >> 2, kk = (i & 3) << 3;
            *(uint4*)&As[r * 40 + kk] =
                *(const uint4*)&A[(size_t)(bm * BM + r) * K + k0 + kk];
        }
        for (int i = tid; i < BN * 4; i += 256) {
            int r = i >> 2, kk = (i & 3) << 3;
            *(uint4*)&Bs[r * 40 + kk] =
                *(const uint4*)&Bt[(size_t)(bn * BN + r) * K + k0 + kk];
        }
        __syncthreads();
        bf16x8 a[FM], b[FN];
#pragma unroll
        for (int m = 0; m < FM; ++m)
            a[m] = *(const bf16x8*)&As[(wr * FM * 16 + m * 16 + l16) * 40 + 8 * quad];
#pragma unroll
        for (int n = 0; n < FN; ++n)
            b[n] = *(const bf16x8*)&Bs[(wc * FN * 16 + n * 16 + l16) * 40 + 8 * quad];
#pragma unroll
        for (int m = 0; m < FM; ++m)
#pragma unroll
            for (int n = 0; n < FN; ++n)
                acc[m][n] = __builtin_amdgcn_mfma_f32_16x16x32_bf16(
                    a[m], b[n], acc[m][n], 0, 0, 0);
        __syncthreads();
    }

#pragma unroll
    for (int m = 0; m < FM; ++m) {
        const int row0 = bm * BM + wr * FM * 16 + m * 16 + quad * 4;
#pragma unroll
        for (int n = 0; n < FN; ++n) {
            const int col = bn * BN + wc * FN * 16 + n * 16 + l16;
            const float bv = bias ? bias[col] : 0.f;
#pragma unroll
            for (int r = 0; r < 4; ++r)
                C[(size_t)(row0 + r) * N + col] = acc[m][n][r] + bv;
        }
    }
}

// ---------------- depthwise causal conv (width 4) + SiLU -> bf16 ----------------
// x_val lives in xr[:, 0:DI] (bf16, ld XRLD)
__global__ __launch_bounds__(256) void conv_silu_kernel(
    const ushort_t* __restrict__ xr, const float* __restrict__ cw,
    const float* __restrict__ cb, ushort_t* __restrict__ xc)
{
    int idx = blockIdx.x * 256 + threadIdx.x;   // over ROWS*DI
    int r = idx >> 11;          // /DI (2048)
    int d = idx & (DI - 1);
    int t = r & (SEQ - 1);      // position within batch
    float acc = cb[d];
#pragma unroll
    for (int k = 0; k < 4; ++k) {
        int tt = t - 3 + k;
        if (tt >= 0)
            acc += bf2f(xr[(size_t)(r - 3 + k) * XRLD + d]) * cw[d * 4 + k];
    }
    float sv = acc / (1.f + __expf(-acc));
    xc[idx] = f2bf(sv);
}

// ---------------- dt_proj + softplus -> dt (fp32, ld DI) ----------------
__global__ __launch_bounds__(256) void dtproj_kernel(
    const float* __restrict__ xdbl, const float* __restrict__ W,
    const float* __restrict__ bias, float* __restrict__ dt)
{
    __shared__ float rows[8][DR];
    const int rb = (blockIdx.x / 8) * 8;
    const int cb0 = (blockIdx.x % 8) * 256;
    const int tid = threadIdx.x;
    if (tid < 128) {
        int rr = tid / 16, cc = (tid % 16) * 4;
        float4 v = *(const float4*)(xdbl + (size_t)(rb + rr) * XPC + cc);
        *(float4*)&rows[rr][cc] = v;
    }
    __syncthreads();
    const int col = cb0 + tid;
    float acc[8] = {};
    for (int k = 0; k < DR; ++k) {
        float w = W[(size_t)k * DI + col];
#pragma unroll
        for (int rr = 0; rr < 8; ++rr) acc[rr] += rows[rr][k] * w;
    }
    float b = bias[col];
#pragma unroll
    for (int rr = 0; rr < 8; ++rr) {
        float z = acc[rr] + b;
        float sp = (z > 20.f) ? z : log1pf(__expf(z));
        dt[(size_t)(rb + rr) * DI + col] = sp;
    }
}

// ---------------- chunked selective scan ----------------
// Block = 256 d-lanes of one (b,chunk). B (and C for pass3) rows staged in LDS.

// Pass 1: local scan from 0; store hend and prodA.
__global__ __launch_bounds__(256) void scan_pass1(
    const float* __restrict__ dt, const ushort_t* __restrict__ xc,
    const float* __restrict__ xdbl, const float* __restrict__ logA,
    float* __restrict__ hend, float* __restrict__ prodA)
{
    __shared__ float Bsm[CL][DS];
    const int bid = blockIdx.x;
    const int bc = bid >> 3;                       // b*NC + c
    const int d = ((bid & 7) << 8) + threadIdx.x;
    const int c = bc & (NC - 1);
    const int b = bc >> 5;
    const int r0 = b * SEQ + c * CL;

    {   // stage B: CL x 16 floats, one float4/thread
        int i = threadIdx.x;
        int r = i >> 2, n4 = (i & 3) << 2;
        *(float4*)&Bsm[r][n4] = *(const float4*)&xdbl[(size_t)(r0 + r) * XPC + DR + n4];
    }
    __syncthreads();

    float A[DS], h[DS];
#pragma unroll
    for (int n = 0; n < DS; ++n) {
        A[n] = -__expf(logA[d * DS + n]);
        h[n] = 0.f;
    }
    float dtsum = 0.f;
#pragma unroll 4
    for (int t = 0; t < CL; ++t) {
        const int r = r0 + t;
        float dtv = dt[(size_t)r * DI + d];
        float xv = bf2f(xc[(size_t)r * DI + d]);
        float bx = dtv * xv;
        dtsum += dtv;
#pragma unroll
        for (int n = 0; n < DS; ++n) {
            float dA = __expf(dtv * A[n]);
            h[n] = dA * h[n] + bx * Bsm[t][n];
        }
    }
#pragma unroll
    for (int n = 0; n < DS; ++n) {
        size_t o = ((size_t)bc * DS + n) * DI + d;
        hend[o] = h[n];
        prodA[o] = __expf(dtsum * A[n]);
    }
}

// Pass 2: sequential combine over the 32 chunks per (b,n,d); hend -> h_in in place.
__global__ __launch_bounds__(256) void scan_pass2(
    float* __restrict__ hend, const float* __restrict__ prodA)
{
    const int gid = blockIdx.x * 256 + threadIdx.x;  // (b*DS+n)*DI + d
    const int d = gid & (DI - 1);
    const int bn = gid >> 11;
    const int n = bn & (DS - 1);
    const int b = bn >> 4;
    float hprev = 0.f;
    for (int c = 0; c < NC; ++c) {
        size_t o = ((size_t)(b * NC + c) * DS + n) * DI + d;
        float tmp = hend[o];
        float P = prodA[o];
        hend[o] = hprev;         // now holds h_in[c]
        hprev = P * hprev + tmp;
    }
}

// Pass 3: re-scan each chunk from h_in; y, +x*D, *silu(res) -> yg (bf16).
__global__ __launch_bounds__(256) void scan_pass3(
    const float* __restrict__ dt, const ushort_t* __restrict__ xc,
    const float* __restrict__ xdbl, const ushort_t* __restrict__ res,
    const float* __restrict__ logA, const float* __restrict__ Dp,
    const float* __restrict__ hin, ushort_t* __restrict__ yg)
{
    __shared__ float BCs[CL][2 * DS];   // [t][0..15]=B, [t][16..31]=C
    const int bid = blockIdx.x;
    const int bc = bid >> 3;
    const int d = ((bid & 7) << 8) + threadIdx.x;
    const int c = bc & (NC - 1);
    const int b = bc >> 5;
    const int r0 = b * SEQ + c * CL;

    {   // stage B|C: CL x 32 floats, two float4/thread
        int i = threadIdx.x;
        int r = i >> 3, c4 = (i & 7) << 2;
        *(float4*)&BCs[r][c4] = *(const float4*)&xdbl[(size_t)(r0 + r) * XPC + DR + c4];
        int i2 = i + 256;
        int r2 = i2 >> 3, c42 = (i2 & 7) << 2;
        *(float4*)&BCs[r2][c42] = *(const float4*)&xdbl[(size_t)(r0 + r2) * XPC + DR + c42];
    }
    __syncthreads();

    float A[DS], h[DS];
#pragma unroll
    for (int n = 0; n < DS; ++n) {
        A[n] = -__expf(logA[d * DS + n]);
        h[n] = hin[((size_t)bc * DS + n) * DI + d];
    }
    const float Dd = Dp[d];
#pragma unroll 4
    for (int t = 0; t < CL; ++t) {
        const int r = r0 + t;
        float dtv = dt[(size_t)r * DI + d];
        float xv = bf2f(xc[(size_t)r * DI + d]);
        float bx = dtv * xv;
        float y = 0.f;
#pragma unroll
        for (int n = 0; n < DS; ++n) {
            float dA = __expf(dtv * A[n]);
            h[n] = dA * h[n] + bx * BCs[t][n];
            y += h[n] * BCs[t][DS + n];
        }
        y += xv * Dd;
        float rv = bf2f(res[(size_t)r * XRLD + d]);
        float sr = rv / (1.f + __expf(-rv));
        yg[(size_t)r * DI + d] = f2bf(y * sr);
    }
}

extern "C" void kernel_launch(void* const* d_in, const int* in_sizes, int n_in,
                              void* d_out, int out_size, void* d_ws, size_t ws_size,
                              hipStream_t stream) {
    const float* x          = (const float*)d_in[0];
    const float* in_proj_w  = (const float*)d_in[1];
    const float* in_proj_b  = (const float*)d_in[2];
    const float* conv_w     = (const float*)d_in[3];
    const float* conv_b     = (const float*)d_in[4];
    const float* x_proj_w   = (const float*)d_in[5];
    const float* dt_proj_w  = (const float*)d_in[6];
    const float* dt_proj_b  = (const float*)d_in[7];
    const float* log_A      = (const float*)d_in[8];
    const float* Dp         = (const float*)d_in[9];
    const float* out_proj_w = (const float*)d_in[10];
    const float* out_proj_b = (const float*)d_in[11];

    // Workspace layout (~134 MB)
    float* ws    = (float*)d_ws;
    float* dt    = ws;                            // ROWS*DI fp32 (32 MB)
    float* xdbl  = dt    + (size_t)ROWS * DI;     // ROWS*XPC fp32 (1.5 MB)
    float* hend  = xdbl  + (size_t)ROWS * XPC;    // BATCH*NC*DS*DI fp32 (8 MB)
    float* prodA = hend  + (size_t)BATCH * NC * DS * DI;  // 8 MB
    ushort_t* xr     = (ushort_t*)(prodA + (size_t)BATCH * NC * DS * DI); // ROWS*XRLD bf16 (32 MB)
    ushort_t* xc_bf  = xr     + (size_t)ROWS * XRLD;      // ROWS*DI bf16 (16 MB)
    ushort_t* yg_bf  = xc_bf  + (size_t)ROWS * DI;        // ROWS*DI bf16 (16 MB)
    ushort_t* x_bf   = yg_bf  + (size_t)ROWS * DI;        // ROWS*DM bf16 (8 MB)
    ushort_t* wt_in  = x_bf   + (size_t)ROWS * DM;        // [2*DI][DM] bf16 (8 MB)
    ushort_t* wt_out = wt_in  + (size_t)2 * DI * DM;      // [DM][DI] bf16 (4 MB)
    ushort_t* wt_xp  = wt_out + (size_t)DM * DI;          // [XPC][DI] bf16

    dim3 blk(256);

    // 0) converts (once per launch)
    cvt_f32_bf16<<<(ROWS * DM / 4) / 256, blk, 0, stream>>>(x, x_bf);
    convt_bf16<<<dim3(2 * DI / 32, DM / 32), blk, 0, stream>>>(in_proj_w, wt_in, DM, 2 * DI);
    convt_bf16<<<dim3(DM / 32, DI / 32), blk, 0, stream>>>(out_proj_w, wt_out, DI, DM);
    convt_bf16<<<dim3(XPC / 32, DI / 32), blk, 0, stream>>>(x_proj_w, wt_xp, DI, XPC);

    // 1) in_proj fused (N=4096): x_bf @ wt_in^T + b -> xr (bf16)
    gemm128_bt<true><<<dim3(XRLD / 128, ROWS / 128), blk, 0, stream>>>(
        x_bf, wt_in, in_proj_b, xr, DM, XRLD);

    // 2) conv + silu: xr[:,0:DI] -> xc (bf16)
    conv_silu_kernel<<<(ROWS * DI) / 256, blk, 0, stream>>>(xr, conv_w, conv_b, xc_bf);

    // 3) x_proj: xc_bf @ wt_xp^T -> xdbl (fp32)
    mfma_gemm_bt<64, 96, 4, 1, 1, 6><<<dim3(1, ROWS / 64), blk, 0, stream>>>(
        xc_bf, wt_xp, nullptr, xdbl, ROWS, XPC, DI);

    // 4) dt_proj + softplus: xdbl -> dt (fp32, ld DI)
    dtproj_kernel<<<(ROWS / 8) * (DI / 256), blk, 0, stream>>>(
        xdbl, dt_proj_w, dt_proj_b, dt);

    // 5) chunked selective scan
    scan_pass1<<<BATCH * NC * (DI / 256), blk, 0, stream>>>(
        dt, xc_bf, xdbl, log_A, hend, prodA);
    scan_pass2<<<(BATCH * DS * DI) / 256, blk, 0, stream>>>(hend, prodA);
    scan_pass3<<<BATCH * NC * (DI / 256), blk, 0, stream>>>(
        dt, xc_bf, xdbl, xr + DI, log_A, Dp, hend, yg_bf);

    // 6) out_proj: yg_bf @ wt_out^T + b -> out (fp32)
    gemm128_bt<false><<<dim3(DM / 128, ROWS / 128), blk, 0, stream>>>(
        yg_bf, wt_out, out_proj_b, (float*)d_out, DI, DM);
}

// Round 8
// 309.955 us; speedup vs baseline: 8.1271x; 1.1389x over previous
//
#include <hip/hip_runtime.h>
#include <hip/hip_bf16.h>

// Problem constants
#define BATCH 2
#define SEQ 2048
#define DM 1024      // d_model
#define DI 2048      // d_inner
#define DS 16        // d_state
#define DR 64        // dt_rank
#define XPC 96       // dt_rank + 2*d_state
#define ROWS 4096    // BATCH*SEQ
#define NC 32        // scan chunks per sequence
#define CL 64        // chunk length = SEQ/NC
#define XRLD 4096    // ld of fused in_proj output (x_val | res), bf16
#define KSXP 8       // xproj split-K factor

typedef __attribute__((ext_vector_type(8))) short bf16x8;
typedef __attribute__((ext_vector_type(4))) float f32x4;
typedef unsigned short ushort_t;
typedef unsigned int u32;

#define GLD_LDS16(g, l) \
    __builtin_amdgcn_global_load_lds((const __attribute__((address_space(1))) u32*)(g), \
                                     (__attribute__((address_space(3))) u32*)(l), 16, 0, 0)

static __device__ __forceinline__ float bf2f(ushort_t u) {
    __hip_bfloat16 b = *(__hip_bfloat16*)&u;
    return __bfloat162float(b);
}
static __device__ __forceinline__ ushort_t f2bf(float f) {
    __hip_bfloat16 b = __float2bfloat16(f);
    return *(ushort_t*)&b;
}

// ---------------- fp32 -> bf16 elementwise convert ----------------
__global__ __launch_bounds__(256) void cvt_f32_bf16(
    const float* __restrict__ in, ushort_t* __restrict__ out)
{
    const size_t i = (size_t)(blockIdx.x * 256 + threadIdx.x) * 4;
    float4 v = *(const float4*)(in + i);
    ushort4 o;
    o.x = f2bf(v.x); o.y = f2bf(v.y); o.z = f2bf(v.z); o.w = f2bf(v.w);
    *(ushort4*)(out + i) = o;
}

// ---------------- transpose + convert: W[K][N] fp32 -> Wt[N][K] bf16 ----------------
__global__ __launch_bounds__(256) void convt_bf16(
    const float* __restrict__ W, ushort_t* __restrict__ Wt, int K, int N)
{
    __shared__ float t[32][33];
    const int n0 = blockIdx.x * 32, k0 = blockIdx.y * 32;
    const int tx = threadIdx.x & 31, ty = threadIdx.x >> 5;  // 32 x 8
#pragma unroll
    for (int i = 0; i < 32; i += 8)
        t[ty + i][tx] = W[(size_t)(k0 + ty + i) * N + n0 + tx];
    __syncthreads();
#pragma unroll
    for (int i = 0; i < 32; i += 8)
        Wt[(size_t)(n0 + ty + i) * K + k0 + tx] = f2bf(t[tx][ty + i]);
}

// ---------------- m97-structure 128x128 bf16 MFMA GEMM ("B^T" operands) ----------------
// C = A[M,K]bf16 @ Bt[N,K]bf16^T + bias; output fp32 or bf16 (BF16OUT).
// 4 waves (2x2), each wave 64x64 = 4x4 frags; BK=32; global_load_lds staging (linear LDS).
// XCD-aware bijective swizzle on flat block id (grid size must be %8==0).
template<bool BF16OUT, typename OutT>
__global__ __launch_bounds__(256) void gemm128_bt(
    const ushort_t* __restrict__ A, const ushort_t* __restrict__ Bt,
    const float* __restrict__ bias, OutT* __restrict__ C,
    int K, int ldc)
{
    __shared__ ushort_t As[128 * 32];
    __shared__ ushort_t Bs[128 * 32];
    const int tid = threadIdx.x;
    const int lane = tid & 63, wid = tid >> 6;
    const int quad = lane >> 4, l16 = lane & 15;
    const int wr = wid >> 1, wc = wid & 1;

    const u32 nwg = gridDim.x * gridDim.y;
    const u32 flat = blockIdx.y * gridDim.x + blockIdx.x;
    const u32 cpx = nwg >> 3;
    const u32 swz = (flat & 7) * cpx + (flat >> 3);
    const int bm = swz / gridDim.x, bn = swz % gridDim.x;

    const int sr = tid >> 2, sk = (tid & 3) << 3;
    const ushort_t* Ag0 = A + (size_t)(bm * 128 + sr) * K + sk;
    const ushort_t* Ag1 = A + (size_t)(bm * 128 + 64 + sr) * K + sk;
    const ushort_t* Bg0 = Bt + (size_t)(bn * 128 + sr) * K + sk;
    const ushort_t* Bg1 = Bt + (size_t)(bn * 128 + 64 + sr) * K + sk;
    ushort_t* As0 = As + tid * 8;
    ushort_t* As1 = As + (tid + 256) * 8;
    ushort_t* Bs0 = Bs + tid * 8;
    ushort_t* Bs1 = Bs + (tid + 256) * 8;

    f32x4 acc[4][4];
#pragma unroll
    for (int m = 0; m < 4; ++m)
#pragma unroll
        for (int n = 0; n < 4; ++n) acc[m][n] = (f32x4){0.f, 0.f, 0.f, 0.f};

    for (int k0 = 0; k0 < K; k0 += 32) {
        GLD_LDS16(Ag0 + k0, As0);
        GLD_LDS16(Ag1 + k0, As1);
        GLD_LDS16(Bg0 + k0, Bs0);
        GLD_LDS16(Bg1 + k0, Bs1);
        __syncthreads();
        bf16x8 a[4], b[4];
#pragma unroll
        for (int m = 0; m < 4; ++m)
            a[m] = *(const bf16x8*)&As[(wr * 64 + m * 16 + l16) * 32 + 8 * quad];
#pragma unroll
        for (int n = 0; n < 4; ++n)
            b[n] = *(const bf16x8*)&Bs[(wc * 64 + n * 16 + l16) * 32 + 8 * quad];
#pragma unroll
        for (int m = 0; m < 4; ++m)
#pragma unroll
            for (int n = 0; n < 4; ++n)
                acc[m][n] = __builtin_amdgcn_mfma_f32_16x16x32_bf16(
                    a[m], b[n], acc[m][n], 0, 0, 0);
        __syncthreads();
    }

#pragma unroll
    for (int m = 0; m < 4; ++m) {
        const int row0 = bm * 128 + wr * 64 + m * 16 + quad * 4;
#pragma unroll
        for (int n = 0; n < 4; ++n) {
            const int col = bn * 128 + wc * 64 + n * 16 + l16;
            const float bv = bias ? bias[col] : 0.f;
#pragma unroll
            for (int r = 0; r < 4; ++r) {
                float v = acc[m][n][r] + bv;
                if constexpr (BF16OUT)
                    ((ushort_t*)C)[(size_t)(row0 + r) * ldc + col] = f2bf(v);
                else
                    ((float*)C)[(size_t)(row0 + r) * ldc + col] = v;
            }
        }
    }
}

// ---------------- split-K x_proj GEMM: 64x96 tile, K slice per blockIdx.x ----------------
// part[ks][ROWS][XPC] += A[64 rows, Kslc] @ Bt[96, Kslc]^T
__global__ __launch_bounds__(256) void xproj_splitk(
    const ushort_t* __restrict__ A, const ushort_t* __restrict__ Bt,
    float* __restrict__ part, int K)
{
    const int BM = 64, BN = XPC;
    __shared__ ushort_t As[64 * 40];
    __shared__ ushort_t Bs[XPC * 40];
    const int tid = threadIdx.x;
    const int wid = tid >> 6, lane = tid & 63;
    const int quad = lane >> 4, l16 = lane & 15;
    const int wr = wid;          // WM=4, WN=1
    const int bm = blockIdx.y;
    const int ks = blockIdx.x;
    const int kslc = K / KSXP;   // 256
    const int kbeg = ks * kslc;

    f32x4 acc[6];
#pragma unroll
    for (int n = 0; n < 6; ++n) acc[n] = (f32x4){0.f, 0.f, 0.f, 0.f};

    for (int k0 = kbeg; k0 < kbeg + kslc; k0 += 32) {
        for (int i = tid; i < BM * 4; i += 256) {
            int r = i >> 2, kk = (i & 3) << 3;
            *(uint4*)&As[r * 40 + kk] =
                *(const uint4*)&A[(size_t)(bm * BM + r) * K + k0 + kk];
        }
        for (int i = tid; i < BN * 4; i += 256) {
            int r = i >> 2, kk = (i & 3) << 3;
            *(uint4*)&Bs[r * 40 + kk] =
                *(const uint4*)&Bt[(size_t)r * K + k0 + kk];
        }
        __syncthreads();
        bf16x8 a, b[6];
        a = *(const bf16x8*)&As[(wr * 16 + l16) * 40 + 8 * quad];
#pragma unroll
        for (int n = 0; n < 6; ++n)
            b[n] = *(const bf16x8*)&Bs[(n * 16 + l16) * 40 + 8 * quad];
#pragma unroll
        for (int n = 0; n < 6; ++n)
            acc[n] = __builtin_amdgcn_mfma_f32_16x16x32_bf16(a, b[n], acc[n], 0, 0, 0);
        __syncthreads();
    }

    float* out = part + (size_t)ks * ROWS * XPC;
    const int row0 = bm * BM + wr * 16 + quad * 4;
#pragma unroll
    for (int n = 0; n < 6; ++n) {
        const int col = n * 16 + l16;
#pragma unroll
        for (int r = 0; r < 4; ++r)
            out[(size_t)(row0 + r) * XPC + col] = acc[n][r];
    }
}

// sum the KSXP partials -> xdbl
__global__ __launch_bounds__(256) void xproj_reduce(
    const float* __restrict__ part, float* __restrict__ xdbl)
{
    const size_t i = (size_t)(blockIdx.x * 256 + threadIdx.x) * 4;
    float4 s = *(const float4*)(part + i);
#pragma unroll
    for (int ks = 1; ks < KSXP; ++ks) {
        float4 v = *(const float4*)(part + (size_t)ks * ROWS * XPC + i);
        s.x += v.x; s.y += v.y; s.z += v.z; s.w += v.w;
    }
    *(float4*)(xdbl + i) = s;
}

// ---------------- depthwise causal conv (width 4) + SiLU -> bf16 ----------------
// x_val lives in xr[:, 0:DI] (bf16, ld XRLD)
__global__ __launch_bounds__(256) void conv_silu_kernel(
    const ushort_t* __restrict__ xr, const float* __restrict__ cw,
    const float* __restrict__ cb, ushort_t* __restrict__ xc)
{
    int idx = blockIdx.x * 256 + threadIdx.x;   // over ROWS*DI
    int r = idx >> 11;          // /DI (2048)
    int d = idx & (DI - 1);
    int t = r & (SEQ - 1);      // position within batch
    float acc = cb[d];
#pragma unroll
    for (int k = 0; k < 4; ++k) {
        int tt = t - 3 + k;
        if (tt >= 0)
            acc += bf2f(xr[(size_t)(r - 3 + k) * XRLD + d]) * cw[d * 4 + k];
    }
    float sv = acc / (1.f + __expf(-acc));
    xc[idx] = f2bf(sv);
}

// ---------------- dt_proj + softplus -> dt (fp32, ld DI) ----------------
__global__ __launch_bounds__(256) void dtproj_kernel(
    const float* __restrict__ xdbl, const float* __restrict__ W,
    const float* __restrict__ bias, float* __restrict__ dt)
{
    __shared__ float rows[8][DR];
    const int rb = (blockIdx.x / 8) * 8;
    const int cb0 = (blockIdx.x % 8) * 256;
    const int tid = threadIdx.x;
    if (tid < 128) {
        int rr = tid / 16, cc = (tid % 16) * 4;
        float4 v = *(const float4*)(xdbl + (size_t)(rb + rr) * XPC + cc);
        *(float4*)&rows[rr][cc] = v;
    }
    __syncthreads();
    const int col = cb0 + tid;
    float acc[8] = {};
    for (int k = 0; k < DR; ++k) {
        float w = W[(size_t)k * DI + col];
#pragma unroll
        for (int rr = 0; rr < 8; ++rr) acc[rr] += rows[rr][k] * w;
    }
    float b = bias[col];
#pragma unroll
    for (int rr = 0; rr < 8; ++rr) {
        float z = acc[rr] + b;
        float sp = (z > 20.f) ? z : log1pf(__expf(z));
        dt[(size_t)(rb + rr) * DI + col] = sp;
    }
}

// ---------------- chunked selective scan ----------------
// Block = 256 d-lanes of one (b,chunk). B (and C for pass3) rows staged in LDS.

// Pass 1: local scan from 0; store hend and prodA.
__global__ __launch_bounds__(256) void scan_pass1(
    const float* __restrict__ dt, const ushort_t* __restrict__ xc,
    const float* __restrict__ xdbl, const float* __restrict__ logA,
    float* __restrict__ hend, float* __restrict__ prodA)
{
    __shared__ float Bsm[CL][DS];
    const int bid = blockIdx.x;
    const int bc = bid >> 3;                       // b*NC + c
    const int d = ((bid & 7) << 8) + threadIdx.x;
    const int c = bc & (NC - 1);
    const int b = bc >> 5;
    const int r0 = b * SEQ + c * CL;

    {   // stage B: CL x 16 floats, one float4/thread
        int i = threadIdx.x;
        int r = i >> 2, n4 = (i & 3) << 2;
        *(float4*)&Bsm[r][n4] = *(const float4*)&xdbl[(size_t)(r0 + r) * XPC + DR + n4];
    }
    __syncthreads();

    float A[DS], h[DS];
#pragma unroll
    for (int n = 0; n < DS; ++n) {
        A[n] = -__expf(logA[d * DS + n]);
        h[n] = 0.f;
    }
    float dtsum = 0.f;
#pragma unroll 4
    for (int t = 0; t < CL; ++t) {
        const int r = r0 + t;
        float dtv = dt[(size_t)r * DI + d];
        float xv = bf2f(xc[(size_t)r * DI + d]);
        float bx = dtv * xv;
        dtsum += dtv;
#pragma unroll
        for (int n = 0; n < DS; ++n) {
            float dA = __expf(dtv * A[n]);
            h[n] = dA * h[n] + bx * Bsm[t][n];
        }
    }
#pragma unroll
    for (int n = 0; n < DS; ++n) {
        size_t o = ((size_t)bc * DS + n) * DI + d;
        hend[o] = h[n];
        prodA[o] = __expf(dtsum * A[n]);
    }
}

// Pass 2: sequential combine; reads hend/prodA, writes INCOMING states to hin.
__global__ __launch_bounds__(256) void scan_pass2(
    const float* __restrict__ hend, const float* __restrict__ prodA,
    float* __restrict__ hin)
{
    const int gid = blockIdx.x * 256 + threadIdx.x;  // (b*DS+n)*DI + d
    const int d = gid & (DI - 1);
    const int bn = gid >> 11;
    const int n = bn & (DS - 1);
    const int b = bn >> 4;
    float hprev = 0.f;
#pragma unroll 8
    for (int c = 0; c < NC; ++c) {
        size_t o = ((size_t)(b * NC + c) * DS + n) * DI + d;
        hin[o] = hprev;
        hprev = prodA[o] * hprev + hend[o];
    }
}

// Pass 3: re-scan each chunk from h_in; y, +x*D, *silu(res) -> yg (bf16).
__global__ __launch_bounds__(256) void scan_pass3(
    const float* __restrict__ dt, const ushort_t* __restrict__ xc,
    const float* __restrict__ xdbl, const ushort_t* __restrict__ res,
    const float* __restrict__ logA, const float* __restrict__ Dp,
    const float* __restrict__ hin, ushort_t* __restrict__ yg)
{
    __shared__ float BCs[CL][2 * DS];   // [t][0..15]=B, [t][16..31]=C
    const int bid = blockIdx.x;
    const int bc = bid >> 3;
    const int d = ((bid & 7) << 8) + threadIdx.x;
    const int c = bc & (NC - 1);
    const int b = bc >> 5;
    const int r0 = b * SEQ + c * CL;

    {   // stage B|C: CL x 32 floats, two float4/thread
        int i = threadIdx.x;
        int r = i >> 3, c4 = (i & 7) << 2;
        *(float4*)&BCs[r][c4] = *(const float4*)&xdbl[(size_t)(r0 + r) * XPC + DR + c4];
        int i2 = i + 256;
        int r2 = i2 >> 3, c42 = (i2 & 7) << 2;
        *(float4*)&BCs[r2][c42] = *(const float4*)&xdbl[(size_t)(r0 + r2) * XPC + DR + c42];
    }
    __syncthreads();

    float A[DS], h[DS];
#pragma unroll
    for (int n = 0; n < DS; ++n) {
        A[n] = -__expf(logA[d * DS + n]);
        h[n] = hin[((size_t)bc * DS + n) * DI + d];
    }
    const float Dd = Dp[d];
#pragma unroll 4
    for (int t = 0; t < CL; ++t) {
        const int r = r0 + t;
        float dtv = dt[(size_t)r * DI + d];
        float xv = bf2f(xc[(size_t)r * DI + d]);
        float bx = dtv * xv;
        float y = 0.f;
#pragma unroll
        for (int n = 0; n < DS; ++n) {
            float dA = __expf(dtv * A[n]);
            h[n] = dA * h[n] + bx * BCs[t][n];
            y += h[n] * BCs[t][DS + n];
        }
        y += xv * Dd;
        float rv = bf2f(res[(size_t)r * XRLD + d]);
        float sr = rv / (1.f + __expf(-rv));
        yg[(size_t)r * DI + d] = f2bf(y * sr);
    }
}

extern "C" void kernel_launch(void* const* d_in, const int* in_sizes, int n_in,
                              void* d_out, int out_size, void* d_ws, size_t ws_size,
                              hipStream_t stream) {
    const float* x          = (const float*)d_in[0];
    const float* in_proj_w  = (const float*)d_in[1];
    const float* in_proj_b  = (const float*)d_in[2];
    const float* conv_w     = (const float*)d_in[3];
    const float* conv_b     = (const float*)d_in[4];
    const float* x_proj_w   = (const float*)d_in[5];
    const float* dt_proj_w  = (const float*)d_in[6];
    const float* dt_proj_b  = (const float*)d_in[7];
    const float* log_A      = (const float*)d_in[8];
    const float* Dp         = (const float*)d_in[9];
    const float* out_proj_w = (const float*)d_in[10];
    const float* out_proj_b = (const float*)d_in[11];

    // Workspace layout (~142 MB)
    float* ws    = (float*)d_ws;
    float* dt    = ws;                            // ROWS*DI fp32 (32 MB); xproj partials overlay (12 MB)
    float* part  = ws;                            //   [KSXP][ROWS][XPC] fp32, dead before dtproj writes dt
    float* xdbl  = dt    + (size_t)ROWS * DI;     // ROWS*XPC fp32 (1.5 MB)
    float* hend  = xdbl  + (size_t)ROWS * XPC;    // 8 MB
    float* prodA = hend  + (size_t)BATCH * NC * DS * DI;  // 8 MB
    float* hin   = prodA + (size_t)BATCH * NC * DS * DI;  // 8 MB
    ushort_t* xr     = (ushort_t*)(hin + (size_t)BATCH * NC * DS * DI); // ROWS*XRLD bf16 (32 MB)
    ushort_t* xc_bf  = xr     + (size_t)ROWS * XRLD;      // ROWS*DI bf16 (16 MB)
    ushort_t* yg_bf  = xc_bf  + (size_t)ROWS * DI;        // ROWS*DI bf16 (16 MB)
    ushort_t* x_bf   = yg_bf  + (size_t)ROWS * DI;        // ROWS*DM bf16 (8 MB)
    ushort_t* wt_in  = x_bf   + (size_t)ROWS * DM;        // [2*DI][DM] bf16 (8 MB)
    ushort_t* wt_out = wt_in  + (size_t)2 * DI * DM;      // [DM][DI] bf16 (4 MB)
    ushort_t* wt_xp  = wt_out + (size_t)DM * DI;          // [XPC][DI] bf16 (0.4 MB)

    dim3 blk(256);

    // 0) converts (once per launch)
    cvt_f32_bf16<<<(ROWS * DM / 4) / 256, blk, 0, stream>>>(x, x_bf);
    convt_bf16<<<dim3(2 * DI / 32, DM / 32), blk, 0, stream>>>(in_proj_w, wt_in, DM, 2 * DI);
    convt_bf16<<<dim3(DM / 32, DI / 32), blk, 0, stream>>>(out_proj_w, wt_out, DI, DM);
    convt_bf16<<<dim3(XPC / 32, DI / 32), blk, 0, stream>>>(x_proj_w, wt_xp, DI, XPC);

    // 1) in_proj fused (N=4096): x_bf @ wt_in^T + b -> xr (bf16)
    gemm128_bt<true><<<dim3(XRLD / 128, ROWS / 128), blk, 0, stream>>>(
        x_bf, wt_in, in_proj_b, xr, DM, XRLD);

    // 2) conv + silu: xr[:,0:DI] -> xc (bf16)
    conv_silu_kernel<<<(ROWS * DI) / 256, blk, 0, stream>>>(xr, conv_w, conv_b, xc_bf);

    // 3) x_proj split-K: xc_bf @ wt_xp^T -> part -> xdbl
    xproj_splitk<<<dim3(KSXP, ROWS / 64), blk, 0, stream>>>(xc_bf, wt_xp, part, DI);
    xproj_reduce<<<(ROWS * XPC / 4) / 256, blk, 0, stream>>>(part, xdbl);

    // 4) dt_proj + softplus: xdbl -> dt (fp32, ld DI; part is dead now)
    dtproj_kernel<<<(ROWS / 8) * (DI / 256), blk, 0, stream>>>(
        xdbl, dt_proj_w, dt_proj_b, dt);

    // 5) chunked selective scan
    scan_pass1<<<BATCH * NC * (DI / 256), blk, 0, stream>>>(
        dt, xc_bf, xdbl, log_A, hend, prodA);
    scan_pass2<<<(BATCH * DS * DI) / 256, blk, 0, stream>>>(hend, prodA, hin);
    scan_pass3<<<BATCH * NC * (DI / 256), blk, 0, stream>>>(
        dt, xc_bf, xdbl, xr + DI, log_A, Dp, hin, yg_bf);

    // 6) out_proj: yg_bf @ wt_out^T + b -> out (fp32)
    gemm128_bt<false><<<dim3(DM / 128, ROWS / 128), blk, 0, stream>>>(
        yg_bf, wt_out, out_proj_b, (float*)d_out, DI, DM);
}

// Round 9
// 296.593 us; speedup vs baseline: 8.4933x; 1.0451x over previous
//
#include <hip/hip_runtime.h>
#include <hip/hip_bf16.h>

// Problem constants
#define BATCH 2
#define SEQ 2048
#define DM 1024      // d_model
#define DI 2048      // d_inner
#define DS 16        // d_state
#define DR 64        // dt_rank
#define XPC 96       // dt_rank + 2*d_state
#define ROWS 4096    // BATCH*SEQ
#define NC 32        // scan chunks per sequence
#define CL 64        // chunk length = SEQ/NC
#define XRLD 4096    // ld of fused in_proj output (x_val | res), bf16
#define KSXP 8       // xproj split-K factor

typedef __attribute__((ext_vector_type(8))) short bf16x8;
typedef __attribute__((ext_vector_type(4))) float f32x4;
typedef unsigned short ushort_t;
typedef unsigned int u32;

#define GLD_LDS16(g, l) \
    __builtin_amdgcn_global_load_lds((const __attribute__((address_space(1))) u32*)(g), \
                                     (__attribute__((address_space(3))) u32*)(l), 16, 0, 0)

static __device__ __forceinline__ float bf2f(ushort_t u) {
    __hip_bfloat16 b = *(__hip_bfloat16*)&u;
    return __bfloat162float(b);
}
static __device__ __forceinline__ ushort_t f2bf(float f) {
    __hip_bfloat16 b = __float2bfloat16(f);
    return *(ushort_t*)&b;
}

// ---------------- fp32 -> bf16 elementwise convert ----------------
__global__ __launch_bounds__(256) void cvt_f32_bf16(
    const float* __restrict__ in, ushort_t* __restrict__ out)
{
    const size_t i = (size_t)(blockIdx.x * 256 + threadIdx.x) * 4;
    float4 v = *(const float4*)(in + i);
    ushort4 o;
    o.x = f2bf(v.x); o.y = f2bf(v.y); o.z = f2bf(v.z); o.w = f2bf(v.w);
    *(ushort4*)(out + i) = o;
}

// ---------------- transpose + convert: W[K][N] fp32 -> Wt[N][K] bf16 ----------------
__global__ __launch_bounds__(256) void convt_bf16(
    const float* __restrict__ W, ushort_t* __restrict__ Wt, int K, int N)
{
    __shared__ float t[32][33];
    const int n0 = blockIdx.x * 32, k0 = blockIdx.y * 32;
    const int tx = threadIdx.x & 31, ty = threadIdx.x >> 5;  // 32 x 8
#pragma unroll
    for (int i = 0; i < 32; i += 8)
        t[ty + i][tx] = W[(size_t)(k0 + ty + i) * N + n0 + tx];
    __syncthreads();
#pragma unroll
    for (int i = 0; i < 32; i += 8)
        Wt[(size_t)(n0 + ty + i) * K + k0 + tx] = f2bf(t[tx][ty + i]);
}

// ---------------- 128x128 bf16 MFMA GEMM, 2-phase double-buffered staging ----------------
// C = A[M,K]bf16 @ Bt[N,K]bf16^T + bias; output fp32 or bf16 (BF16OUT).
// 4 waves (2x2), each wave 64x64 = 4x4 frags; BK=32; global_load_lds into
// double-buffered linear LDS: STAGE(next) issued before COMPUTE(cur), one
// barrier per K-step -> HBM latency hides under ds_read+MFMA.
template<bool BF16OUT, typename OutT>
__global__ __launch_bounds__(256) void gemm128_bt(
    const ushort_t* __restrict__ A, const ushort_t* __restrict__ Bt,
    const float* __restrict__ bias, OutT* __restrict__ C,
    int K, int ldc)
{
    __shared__ ushort_t As[2][128 * 32];
    __shared__ ushort_t Bs[2][128 * 32];
    const int tid = threadIdx.x;
    const int lane = tid & 63, wid = tid >> 6;
    const int quad = lane >> 4, l16 = lane & 15;
    const int wr = wid >> 1, wc = wid & 1;
    const int bm = blockIdx.y, bn = blockIdx.x;

    const int sr = tid >> 2, sk = (tid & 3) << 3;
    const ushort_t* Ag0 = A + (size_t)(bm * 128 + sr) * K + sk;
    const ushort_t* Ag1 = A + (size_t)(bm * 128 + 64 + sr) * K + sk;
    const ushort_t* Bg0 = Bt + (size_t)(bn * 128 + sr) * K + sk;
    const ushort_t* Bg1 = Bt + (size_t)(bn * 128 + 64 + sr) * K + sk;

    f32x4 acc[4][4];
#pragma unroll
    for (int m = 0; m < 4; ++m)
#pragma unroll
        for (int n = 0; n < 4; ++n) acc[m][n] = (f32x4){0.f, 0.f, 0.f, 0.f};

    auto stage = [&](int buf, int kk) {
        GLD_LDS16(Ag0 + kk, &As[buf][tid * 8]);
        GLD_LDS16(Ag1 + kk, &As[buf][(tid + 256) * 8]);
        GLD_LDS16(Bg0 + kk, &Bs[buf][tid * 8]);
        GLD_LDS16(Bg1 + kk, &Bs[buf][(tid + 256) * 8]);
    };
    auto compute = [&](int buf) {
        bf16x8 a[4], b[4];
#pragma unroll
        for (int m = 0; m < 4; ++m)
            a[m] = *(const bf16x8*)&As[buf][(wr * 64 + m * 16 + l16) * 32 + 8 * quad];
#pragma unroll
        for (int n = 0; n < 4; ++n)
            b[n] = *(const bf16x8*)&Bs[buf][(wc * 64 + n * 16 + l16) * 32 + 8 * quad];
#pragma unroll
        for (int m = 0; m < 4; ++m)
#pragma unroll
            for (int n = 0; n < 4; ++n)
                acc[m][n] = __builtin_amdgcn_mfma_f32_16x16x32_bf16(
                    a[m], b[n], acc[m][n], 0, 0, 0);
    };

    const int nt = K >> 5;            // K/32, even for all our shapes
    stage(0, 0);
    for (int t = 0; t < nt; t += 2) {
        __syncthreads();              // buf0 staged; prev reads of buf1 done
        if (t + 1 < nt) stage(1, (t + 1) << 5);
        compute(0);
        __syncthreads();              // buf1 staged; reads of buf0 done
        if (t + 2 < nt) stage(0, (t + 2) << 5);
        compute(1);
    }

#pragma unroll
    for (int m = 0; m < 4; ++m) {
        const int row0 = bm * 128 + wr * 64 + m * 16 + quad * 4;
#pragma unroll
        for (int n = 0; n < 4; ++n) {
            const int col = bn * 128 + wc * 64 + n * 16 + l16;
            const float bv = bias ? bias[col] : 0.f;
#pragma unroll
            for (int r = 0; r < 4; ++r) {
                float v = acc[m][n][r] + bv;
                if constexpr (BF16OUT)
                    ((ushort_t*)C)[(size_t)(row0 + r) * ldc + col] = f2bf(v);
                else
                    ((float*)C)[(size_t)(row0 + r) * ldc + col] = v;
            }
        }
    }
}

// ---------------- split-K x_proj GEMM: 64x96 tile, K slice per blockIdx.x ----------------
// part[ks][ROWS][XPC] = A[64 rows, Kslc] @ Bt[96, Kslc]^T
__global__ __launch_bounds__(256) void xproj_splitk(
    const ushort_t* __restrict__ A, const ushort_t* __restrict__ Bt,
    float* __restrict__ part, int K)
{
    const int BM = 64, BN = XPC;
    __shared__ ushort_t As[64 * 40];
    __shared__ ushort_t Bs[XPC * 40];
    const int tid = threadIdx.x;
    const int wid = tid >> 6, lane = tid & 63;
    const int quad = lane >> 4, l16 = lane & 15;
    const int wr = wid;          // WM=4, WN=1
    const int bm = blockIdx.y;
    const int ks = blockIdx.x;
    const int kslc = K / KSXP;   // 256
    const int kbeg = ks * kslc;

    f32x4 acc[6];
#pragma unroll
    for (int n = 0; n < 6; ++n) acc[n] = (f32x4){0.f, 0.f, 0.f, 0.f};

    for (int k0 = kbeg; k0 < kbeg + kslc; k0 += 32) {
        for (int i = tid; i < BM * 4; i += 256) {
            int r = i >> 2, kk = (i & 3) << 3;
            *(uint4*)&As[r * 40 + kk] =
                *(const uint4*)&A[(size_t)(bm * BM + r) * K + k0 + kk];
        }
        for (int i = tid; i < BN * 4; i += 256) {
            int r = i >> 2, kk = (i & 3) << 3;
            *(uint4*)&Bs[r * 40 + kk] =
                *(const uint4*)&Bt[(size_t)r * K + k0 + kk];
        }
        __syncthreads();
        bf16x8 a, b[6];
        a = *(const bf16x8*)&As[(wr * 16 + l16) * 40 + 8 * quad];
#pragma unroll
        for (int n = 0; n < 6; ++n)
            b[n] = *(const bf16x8*)&Bs[(n * 16 + l16) * 40 + 8 * quad];
#pragma unroll
        for (int n = 0; n < 6; ++n)
            acc[n] = __builtin_amdgcn_mfma_f32_16x16x32_bf16(a, b[n], acc[n], 0, 0, 0);
        __syncthreads();
    }

    float* out = part + (size_t)ks * ROWS * XPC;
    const int row0 = bm * BM + wr * 16 + quad * 4;
#pragma unroll
    for (int n = 0; n < 6; ++n) {
        const int col = n * 16 + l16;
#pragma unroll
        for (int r = 0; r < 4; ++r)
            out[(size_t)(row0 + r) * XPC + col] = acc[n][r];
    }
}

// sum the KSXP partials -> xdbl
__global__ __launch_bounds__(256) void xproj_reduce(
    const float* __restrict__ part, float* __restrict__ xdbl)
{
    const size_t i = (size_t)(blockIdx.x * 256 + threadIdx.x) * 4;
    float4 s = *(const float4*)(part + i);
#pragma unroll
    for (int ks = 1; ks < KSXP; ++ks) {
        float4 v = *(const float4*)(part + (size_t)ks * ROWS * XPC + i);
        s.x += v.x; s.y += v.y; s.z += v.z; s.w += v.w;
    }
    *(float4*)(xdbl + i) = s;
}

// ---------------- depthwise causal conv (width 4) + SiLU -> bf16 ----------------
// x_val lives in xr[:, 0:DI] (bf16, ld XRLD)
__global__ __launch_bounds__(256) void conv_silu_kernel(
    const ushort_t* __restrict__ xr, const float* __restrict__ cw,
    const float* __restrict__ cb, ushort_t* __restrict__ xc)
{
    int idx = blockIdx.x * 256 + threadIdx.x;   // over ROWS*DI
    int r = idx >> 11;          // /DI (2048)
    int d = idx & (DI - 1);
    int t = r & (SEQ - 1);      // position within batch
    float acc = cb[d];
#pragma unroll
    for (int k = 0; k < 4; ++k) {
        int tt = t - 3 + k;
        if (tt >= 0)
            acc += bf2f(xr[(size_t)(r - 3 + k) * XRLD + d]) * cw[d * 4 + k];
    }
    float sv = acc / (1.f + __expf(-acc));
    xc[idx] = f2bf(sv);
}

// ---------------- dt_proj + softplus -> dt (fp32, ld DI) ----------------
__global__ __launch_bounds__(256) void dtproj_kernel(
    const float* __restrict__ xdbl, const float* __restrict__ W,
    const float* __restrict__ bias, float* __restrict__ dt)
{
    __shared__ float rows[8][DR];
    const int rb = (blockIdx.x / 8) * 8;
    const int cb0 = (blockIdx.x % 8) * 256;
    const int tid = threadIdx.x;
    if (tid < 128) {
        int rr = tid / 16, cc = (tid % 16) * 4;
        float4 v = *(const float4*)(xdbl + (size_t)(rb + rr) * XPC + cc);
        *(float4*)&rows[rr][cc] = v;
    }
    __syncthreads();
    const int col = cb0 + tid;
    float acc[8] = {};
    for (int k = 0; k < DR; ++k) {
        float w = W[(size_t)k * DI + col];
#pragma unroll
        for (int rr = 0; rr < 8; ++rr) acc[rr] += rows[rr][k] * w;
    }
    float b = bias[col];
#pragma unroll
    for (int rr = 0; rr < 8; ++rr) {
        float z = acc[rr] + b;
        float sp = (z > 20.f) ? z : log1pf(__expf(z));
        dt[(size_t)(rb + rr) * DI + col] = sp;
    }
}

// ---------------- chunked selective scan ----------------
// Block = 256 d-lanes of one (b,chunk). B (and C for pass3) rows staged in LDS.

// Pass 1: local scan from 0; store hend and prodA.
__global__ __launch_bounds__(256) void scan_pass1(
    const float* __restrict__ dt, const ushort_t* __restrict__ xc,
    const float* __restrict__ xdbl, const float* __restrict__ logA,
    float* __restrict__ hend, float* __restrict__ prodA)
{
    __shared__ float Bsm[CL][DS];
    const int bid = blockIdx.x;
    const int bc = bid >> 3;                       // b*NC + c
    const int d = ((bid & 7) << 8) + threadIdx.x;
    const int c = bc & (NC - 1);
    const int b = bc >> 5;
    const int r0 = b * SEQ + c * CL;

    {   // stage B: CL x 16 floats, one float4/thread
        int i = threadIdx.x;
        int r = i >> 2, n4 = (i & 3) << 2;
        *(float4*)&Bsm[r][n4] = *(const float4*)&xdbl[(size_t)(r0 + r) * XPC + DR + n4];
    }
    __syncthreads();

    float A[DS], h[DS];
#pragma unroll
    for (int n = 0; n < DS; ++n) {
        A[n] = -__expf(logA[d * DS + n]);
        h[n] = 0.f;
    }
    float dtsum = 0.f;
#pragma unroll 4
    for (int t = 0; t < CL; ++t) {
        const int r = r0 + t;
        float dtv = dt[(size_t)r * DI + d];
        float xv = bf2f(xc[(size_t)r * DI + d]);
        float bx = dtv * xv;
        dtsum += dtv;
#pragma unroll
        for (int n = 0; n < DS; ++n) {
            float dA = __expf(dtv * A[n]);
            h[n] = dA * h[n] + bx * Bsm[t][n];
        }
    }
#pragma unroll
    for (int n = 0; n < DS; ++n) {
        size_t o = ((size_t)bc * DS + n) * DI + d;
        hend[o] = h[n];
        prodA[o] = __expf(dtsum * A[n]);
    }
}

// Pass 2: sequential combine; reads hend/prodA, writes INCOMING states to hin.
__global__ __launch_bounds__(256) void scan_pass2(
    const float* __restrict__ hend, const float* __restrict__ prodA,
    float* __restrict__ hin)
{
    const int gid = blockIdx.x * 256 + threadIdx.x;  // (b*DS+n)*DI + d
    const int d = gid & (DI - 1);
    const int bn = gid >> 11;
    const int n = bn & (DS - 1);
    const int b = bn >> 4;
    float hprev = 0.f;
#pragma unroll 8
    for (int c = 0; c < NC; ++c) {
        size_t o = ((size_t)(b * NC + c) * DS + n) * DI + d;
        hin[o] = hprev;
        hprev = prodA[o] * hprev + hend[o];
    }
}

// Pass 3: re-scan each chunk from h_in; y, +x*D, *silu(res) -> yg (bf16).
__global__ __launch_bounds__(256) void scan_pass3(
    const float* __restrict__ dt, const ushort_t* __restrict__ xc,
    const float* __restrict__ xdbl, const ushort_t* __restrict__ res,
    const float* __restrict__ logA, const float* __restrict__ Dp,
    const float* __restrict__ hin, ushort_t* __restrict__ yg)
{
    __shared__ float BCs[CL][2 * DS];   // [t][0..15]=B, [t][16..31]=C
    const int bid = blockIdx.x;
    const int bc = bid >> 3;
    const int d = ((bid & 7) << 8) + threadIdx.x;
    const int c = bc & (NC - 1);
    const int b = bc >> 5;
    const int r0 = b * SEQ + c * CL;

    {   // stage B|C: CL x 32 floats, two float4/thread
        int i = threadIdx.x;
        int r = i >> 3, c4 = (i & 7) << 2;
        *(float4*)&BCs[r][c4] = *(const float4*)&xdbl[(size_t)(r0 + r) * XPC + DR + c4];
        int i2 = i + 256;
        int r2 = i2 >> 3, c42 = (i2 & 7) << 2;
        *(float4*)&BCs[r2][c42] = *(const float4*)&xdbl[(size_t)(r0 + r2) * XPC + DR + c42];
    }
    __syncthreads();

    float A[DS], h[DS];
#pragma unroll
    for (int n = 0; n < DS; ++n) {
        A[n] = -__expf(logA[d * DS + n]);
        h[n] = hin[((size_t)bc * DS + n) * DI + d];
    }
    const float Dd = Dp[d];
#pragma unroll 4
    for (int t = 0; t < CL; ++t) {
        const int r = r0 + t;
        float dtv = dt[(size_t)r * DI + d];
        float xv = bf2f(xc[(size_t)r * DI + d]);
        float bx = dtv * xv;
        float y = 0.f;
#pragma unroll
        for (int n = 0; n < DS; ++n) {
            float dA = __expf(dtv * A[n]);
            h[n] = dA * h[n] + bx * BCs[t][n];
            y += h[n] * BCs[t][DS + n];
        }
        y += xv * Dd;
        float rv = bf2f(res[(size_t)r * XRLD + d]);
        float sr = rv / (1.f + __expf(-rv));
        yg[(size_t)r * DI + d] = f2bf(y * sr);
    }
}

extern "C" void kernel_launch(void* const* d_in, const int* in_sizes, int n_in,
                              void* d_out, int out_size, void* d_ws, size_t ws_size,
                              hipStream_t stream) {
    const float* x          = (const float*)d_in[0];
    const float* in_proj_w  = (const float*)d_in[1];
    const float* in_proj_b  = (const float*)d_in[2];
    const float* conv_w     = (const float*)d_in[3];
    const float* conv_b     = (const float*)d_in[4];
    const float* x_proj_w   = (const float*)d_in[5];
    const float* dt_proj_w  = (const float*)d_in[6];
    const float* dt_proj_b  = (const float*)d_in[7];
    const float* log_A      = (const float*)d_in[8];
    const float* Dp         = (const float*)d_in[9];
    const float* out_proj_w = (const float*)d_in[10];
    const float* out_proj_b = (const float*)d_in[11];

    // Workspace layout (~142 MB)
    float* ws    = (float*)d_ws;
    float* dt    = ws;                            // ROWS*DI fp32 (32 MB); xproj partials overlay (12 MB)
    float* part  = ws;                            //   [KSXP][ROWS][XPC] fp32, dead before dtproj writes dt
    float* xdbl  = dt    + (size_t)ROWS * DI;     // ROWS*XPC fp32 (1.5 MB)
    float* hend  = xdbl  + (size_t)ROWS * XPC;    // 8 MB
    float* prodA = hend  + (size_t)BATCH * NC * DS * DI;  // 8 MB
    float* hin   = prodA + (size_t)BATCH * NC * DS * DI;  // 8 MB
    ushort_t* xr     = (ushort_t*)(hin + (size_t)BATCH * NC * DS * DI); // ROWS*XRLD bf16 (32 MB)
    ushort_t* xc_bf  = xr     + (size_t)ROWS * XRLD;      // ROWS*DI bf16 (16 MB)
    ushort_t* yg_bf  = xc_bf  + (size_t)ROWS * DI;        // ROWS*DI bf16 (16 MB)
    ushort_t* x_bf   = yg_bf  + (size_t)ROWS * DI;        // ROWS*DM bf16 (8 MB)
    ushort_t* wt_in  = x_bf   + (size_t)ROWS * DM;        // [2*DI][DM] bf16 (8 MB)
    ushort_t* wt_out = wt_in  + (size_t)2 * DI * DM;      // [DM][DI] bf16 (4 MB)
    ushort_t* wt_xp  = wt_out + (size_t)DM * DI;          // [XPC][DI] bf16 (0.4 MB)

    dim3 blk(256);

    // 0) converts (once per launch)
    cvt_f32_bf16<<<(ROWS * DM / 4) / 256, blk, 0, stream>>>(x, x_bf);
    convt_bf16<<<dim3(2 * DI / 32, DM / 32), blk, 0, stream>>>(in_proj_w, wt_in, DM, 2 * DI);
    convt_bf16<<<dim3(DM / 32, DI / 32), blk, 0, stream>>>(out_proj_w, wt_out, DI, DM);
    convt_bf16<<<dim3(XPC / 32, DI / 32), blk, 0, stream>>>(x_proj_w, wt_xp, DI, XPC);

    // 1) in_proj fused (N=4096): x_bf @ wt_in^T + b -> xr (bf16)
    gemm128_bt<true><<<dim3(XRLD / 128, ROWS / 128), blk, 0, stream>>>(
        x_bf, wt_in, in_proj_b, xr, DM, XRLD);

    // 2) conv + silu: xr[:,0:DI] -> xc (bf16)
    conv_silu_kernel<<<(ROWS * DI) / 256, blk, 0, stream>>>(xr, conv_w, conv_b, xc_bf);

    // 3) x_proj split-K: xc_bf @ wt_xp^T -> part -> xdbl
    xproj_splitk<<<dim3(KSXP, ROWS / 64), blk, 0, stream>>>(xc_bf, wt_xp, part, DI);
    xproj_reduce<<<(ROWS * XPC / 4) / 256, blk, 0, stream>>>(part, xdbl);

    // 4) dt_proj + softplus: xdbl -> dt (fp32, ld DI; part is dead now)
    dtproj_kernel<<<(ROWS / 8) * (DI / 256), blk, 0, stream>>>(
        xdbl, dt_proj_w, dt_proj_b, dt);

    // 5) chunked selective scan
    scan_pass1<<<BATCH * NC * (DI / 256), blk, 0, stream>>>(
        dt, xc_bf, xdbl, log_A, hend, prodA);
    scan_pass2<<<(BATCH * DS * DI) / 256, blk, 0, stream>>>(hend, prodA, hin);
    scan_pass3<<<BATCH * NC * (DI / 256), blk, 0, stream>>>(
        dt, xc_bf, xdbl, xr + DI, log_A, Dp, hin, yg_bf);

    // 6) out_proj: yg_bf @ wt_out^T + b -> out (fp32)
    gemm128_bt<false><<<dim3(DM / 128, ROWS / 128), blk, 0, stream>>>(
        yg_bf, wt_out, out_proj_b, (float*)d_out, DI, DM);
}

// Round 10
// 287.302 us; speedup vs baseline: 8.7679x; 1.0323x over previous
//
#include <hip/hip_runtime.h>
#include <hip/hip_bf16.h>

// Problem constants
#define BATCH 2
#define SEQ 2048
#define DM 1024      // d_model
#define DI 2048      // d_inner
#define DS 16        // d_state
#define DR 64        // dt_rank
#define XPC 96       // dt_rank + 2*d_state
#define ROWS 4096    // BATCH*SEQ
#define NC 32        // scan chunks per sequence
#define CL 64        // chunk length = SEQ/NC
#define XRLD 4096    // ld of fused in_proj output (x_val | res), bf16
#define KSXP 8       // xproj split-K factor

typedef __attribute__((ext_vector_type(8))) short bf16x8;
typedef __attribute__((ext_vector_type(4))) float f32x4;
typedef unsigned short ushort_t;
typedef unsigned int u32;

#define GLD_LDS16(g, l) \
    __builtin_amdgcn_global_load_lds((const __attribute__((address_space(1))) u32*)(g), \
                                     (__attribute__((address_space(3))) u32*)(l), 16, 0, 0)

static __device__ __forceinline__ float bf2f(ushort_t u) {
    __hip_bfloat16 b = *(__hip_bfloat16*)&u;
    return __bfloat162float(b);
}
static __device__ __forceinline__ ushort_t f2bf(float f) {
    __hip_bfloat16 b = __float2bfloat16(f);
    return *(ushort_t*)&b;
}

// ---------------- fp32 -> bf16 elementwise convert ----------------
__global__ __launch_bounds__(256) void cvt_f32_bf16(
    const float* __restrict__ in, ushort_t* __restrict__ out)
{
    const size_t i = (size_t)(blockIdx.x * 256 + threadIdx.x) * 4;
    float4 v = *(const float4*)(in + i);
    ushort4 o;
    o.x = f2bf(v.x); o.y = f2bf(v.y); o.z = f2bf(v.z); o.w = f2bf(v.w);
    *(ushort4*)(out + i) = o;
}

// ---------------- transpose + convert: W[K][N] fp32 -> Wt[N][K] bf16 ----------------
__global__ __launch_bounds__(256) void convt_bf16(
    const float* __restrict__ W, ushort_t* __restrict__ Wt, int K, int N)
{
    __shared__ float t[32][33];
    const int n0 = blockIdx.x * 32, k0 = blockIdx.y * 32;
    const int tx = threadIdx.x & 31, ty = threadIdx.x >> 5;  // 32 x 8
#pragma unroll
    for (int i = 0; i < 32; i += 8)
        t[ty + i][tx] = W[(size_t)(k0 + ty + i) * N + n0 + tx];
    __syncthreads();
#pragma unroll
    for (int i = 0; i < 32; i += 8)
        Wt[(size_t)(n0 + ty + i) * K + k0 + tx] = f2bf(t[tx][ty + i]);
}

// ---------------- 128x128 bf16 MFMA GEMM, 2-phase double-buffered staging ----------------
// C = A[M,K]bf16 @ Bt[N,K]bf16^T (+bias / softplus epilogue per EPI).
// EPI: 0 = bias, fp32 out; 1 = bias, bf16 out; 2 = softplus(v+bias), fp32 out.
// 4 waves (2x2), each wave 64x64 = 4x4 frags; BK=32; global_load_lds into
// double-buffered linear LDS: STAGE(next) issued before COMPUTE(cur).
template<int EPI, typename OutT>
__global__ __launch_bounds__(256) void gemm128_bt(
    const ushort_t* __restrict__ A, const ushort_t* __restrict__ Bt,
    const float* __restrict__ bias, OutT* __restrict__ C,
    int K, int ldc)
{
    __shared__ ushort_t As[2][128 * 32];
    __shared__ ushort_t Bs[2][128 * 32];
    const int tid = threadIdx.x;
    const int lane = tid & 63, wid = tid >> 6;
    const int quad = lane >> 4, l16 = lane & 15;
    const int wr = wid >> 1, wc = wid & 1;
    const int bm = blockIdx.y, bn = blockIdx.x;

    const int sr = tid >> 2, sk = (tid & 3) << 3;
    const ushort_t* Ag0 = A + (size_t)(bm * 128 + sr) * K + sk;
    const ushort_t* Ag1 = A + (size_t)(bm * 128 + 64 + sr) * K + sk;
    const ushort_t* Bg0 = Bt + (size_t)(bn * 128 + sr) * K + sk;
    const ushort_t* Bg1 = Bt + (size_t)(bn * 128 + 64 + sr) * K + sk;

    f32x4 acc[4][4];
#pragma unroll
    for (int m = 0; m < 4; ++m)
#pragma unroll
        for (int n = 0; n < 4; ++n) acc[m][n] = (f32x4){0.f, 0.f, 0.f, 0.f};

    auto stage = [&](int buf, int kk) {
        GLD_LDS16(Ag0 + kk, &As[buf][tid * 8]);
        GLD_LDS16(Ag1 + kk, &As[buf][(tid + 256) * 8]);
        GLD_LDS16(Bg0 + kk, &Bs[buf][tid * 8]);
        GLD_LDS16(Bg1 + kk, &Bs[buf][(tid + 256) * 8]);
    };
    auto compute = [&](int buf) {
        bf16x8 a[4], b[4];
#pragma unroll
        for (int m = 0; m < 4; ++m)
            a[m] = *(const bf16x8*)&As[buf][(wr * 64 + m * 16 + l16) * 32 + 8 * quad];
#pragma unroll
        for (int n = 0; n < 4; ++n)
            b[n] = *(const bf16x8*)&Bs[buf][(wc * 64 + n * 16 + l16) * 32 + 8 * quad];
#pragma unroll
        for (int m = 0; m < 4; ++m)
#pragma unroll
            for (int n = 0; n < 4; ++n)
                acc[m][n] = __builtin_amdgcn_mfma_f32_16x16x32_bf16(
                    a[m], b[n], acc[m][n], 0, 0, 0);
    };

    const int nt = K >> 5;            // K/32, even for all our shapes
    stage(0, 0);
    for (int t = 0; t < nt; t += 2) {
        __syncthreads();              // buf0 staged; prev reads of buf1 done
        if (t + 1 < nt) stage(1, (t + 1) << 5);
        compute(0);
        __syncthreads();              // buf1 staged; reads of buf0 done
        if (t + 2 < nt) stage(0, (t + 2) << 5);
        compute(1);
    }

#pragma unroll
    for (int m = 0; m < 4; ++m) {
        const int row0 = bm * 128 + wr * 64 + m * 16 + quad * 4;
#pragma unroll
        for (int n = 0; n < 4; ++n) {
            const int col = bn * 128 + wc * 64 + n * 16 + l16;
            const float bv = bias ? bias[col] : 0.f;
#pragma unroll
            for (int r = 0; r < 4; ++r) {
                float v = acc[m][n][r] + bv;
                if constexpr (EPI == 1) {
                    ((ushort_t*)C)[(size_t)(row0 + r) * ldc + col] = f2bf(v);
                } else if constexpr (EPI == 2) {
                    float sp = (v > 20.f) ? v : log1pf(__expf(v));
                    ((float*)C)[(size_t)(row0 + r) * ldc + col] = sp;
                } else {
                    ((float*)C)[(size_t)(row0 + r) * ldc + col] = v;
                }
            }
        }
    }
}

// ---------------- split-K x_proj GEMM: 64x96 tile, K slice per blockIdx.x ----------------
// part[ks][ROWS][XPC] = A[64 rows, Kslc] @ Bt[96, Kslc]^T
__global__ __launch_bounds__(256) void xproj_splitk(
    const ushort_t* __restrict__ A, const ushort_t* __restrict__ Bt,
    float* __restrict__ part, int K)
{
    const int BM = 64, BN = XPC;
    __shared__ ushort_t As[64 * 40];
    __shared__ ushort_t Bs[XPC * 40];
    const int tid = threadIdx.x;
    const int wid = tid >> 6, lane = tid & 63;
    const int quad = lane >> 4, l16 = lane & 15;
    const int wr = wid;          // WM=4, WN=1
    const int bm = blockIdx.y;
    const int ks = blockIdx.x;
    const int kslc = K / KSXP;   // 256
    const int kbeg = ks * kslc;

    f32x4 acc[6];
#pragma unroll
    for (int n = 0; n < 6; ++n) acc[n] = (f32x4){0.f, 0.f, 0.f, 0.f};

    for (int k0 = kbeg; k0 < kbeg + kslc; k0 += 32) {
        for (int i = tid; i < BM * 4; i += 256) {
            int r = i >> 2, kk = (i & 3) << 3;
            *(uint4*)&As[r * 40 + kk] =
                *(const uint4*)&A[(size_t)(bm * BM + r) * K + k0 + kk];
        }
        for (int i = tid; i < BN * 4; i += 256) {
            int r = i >> 2, kk = (i & 3) << 3;
            *(uint4*)&Bs[r * 40 + kk] =
                *(const uint4*)&Bt[(size_t)r * K + k0 + kk];
        }
        __syncthreads();
        bf16x8 a, b[6];
        a = *(const bf16x8*)&As[(wr * 16 + l16) * 40 + 8 * quad];
#pragma unroll
        for (int n = 0; n < 6; ++n)
            b[n] = *(const bf16x8*)&Bs[(n * 16 + l16) * 40 + 8 * quad];
#pragma unroll
        for (int n = 0; n < 6; ++n)
            acc[n] = __builtin_amdgcn_mfma_f32_16x16x32_bf16(a, b[n], acc[n], 0, 0, 0);
        __syncthreads();
    }

    float* out = part + (size_t)ks * ROWS * XPC;
    const int row0 = bm * BM + wr * 16 + quad * 4;
#pragma unroll
    for (int n = 0; n < 6; ++n) {
        const int col = n * 16 + l16;
#pragma unroll
        for (int r = 0; r < 4; ++r)
            out[(size_t)(row0 + r) * XPC + col] = acc[n][r];
    }
}

// sum the KSXP partials -> xdbl (fp32) ; also emit cols 0..DR-1 as bf16 (xdt)
__global__ __launch_bounds__(256) void xproj_reduce(
    const float* __restrict__ part, float* __restrict__ xdbl,
    ushort_t* __restrict__ xdt)
{
    const size_t i = (size_t)(blockIdx.x * 256 + threadIdx.x) * 4;
    float4 s = *(const float4*)(part + i);
#pragma unroll
    for (int ks = 1; ks < KSXP; ++ks) {
        float4 v = *(const float4*)(part + (size_t)ks * ROWS * XPC + i);
        s.x += v.x; s.y += v.y; s.z += v.z; s.w += v.w;
    }
    *(float4*)(xdbl + i) = s;
    const int col = (int)(i % XPC);
    if (col < DR) {
        const int row = (int)(i / XPC);
        ushort4 o;
        o.x = f2bf(s.x); o.y = f2bf(s.y); o.z = f2bf(s.z); o.w = f2bf(s.w);
        *(ushort4*)(xdt + (size_t)row * DR + col) = o;
    }
}

// ---------------- depthwise causal conv (width 4) + SiLU -> bf16 ----------------
// x_val lives in xr[:, 0:DI] (bf16, ld XRLD)
__global__ __launch_bounds__(256) void conv_silu_kernel(
    const ushort_t* __restrict__ xr, const float* __restrict__ cw,
    const float* __restrict__ cb, ushort_t* __restrict__ xc)
{
    int idx = blockIdx.x * 256 + threadIdx.x;   // over ROWS*DI
    int r = idx >> 11;          // /DI (2048)
    int d = idx & (DI - 1);
    int t = r & (SEQ - 1);      // position within batch
    float acc = cb[d];
#pragma unroll
    for (int k = 0; k < 4; ++k) {
        int tt = t - 3 + k;
        if (tt >= 0)
            acc += bf2f(xr[(size_t)(r - 3 + k) * XRLD + d]) * cw[d * 4 + k];
    }
    float sv = acc / (1.f + __expf(-acc));
    xc[idx] = f2bf(sv);
}

// ---------------- chunked selective scan ----------------
// Block = 256 d-lanes of one (b,chunk). B (and C for pass3) rows staged in LDS.

// Pass 1: local scan from 0; store hend and prodA.
__global__ __launch_bounds__(256) void scan_pass1(
    const float* __restrict__ dt, const ushort_t* __restrict__ xc,
    const float* __restrict__ xdbl, const float* __restrict__ logA,
    float* __restrict__ hend, float* __restrict__ prodA)
{
    __shared__ float Bsm[CL][DS];
    const int bid = blockIdx.x;
    const int bc = bid >> 3;                       // b*NC + c
    const int d = ((bid & 7) << 8) + threadIdx.x;
    const int c = bc & (NC - 1);
    const int b = bc >> 5;
    const int r0 = b * SEQ + c * CL;

    {   // stage B: CL x 16 floats, one float4/thread
        int i = threadIdx.x;
        int r = i >> 2, n4 = (i & 3) << 2;
        *(float4*)&Bsm[r][n4] = *(const float4*)&xdbl[(size_t)(r0 + r) * XPC + DR + n4];
    }
    __syncthreads();

    float A[DS], h[DS];
#pragma unroll
    for (int n = 0; n < DS; ++n) {
        A[n] = -__expf(logA[d * DS + n]);
        h[n] = 0.f;
    }
    float dtsum = 0.f;
#pragma unroll 4
    for (int t = 0; t < CL; ++t) {
        const int r = r0 + t;
        float dtv = dt[(size_t)r * DI + d];
        float xv = bf2f(xc[(size_t)r * DI + d]);
        float bx = dtv * xv;
        dtsum += dtv;
#pragma unroll
        for (int n = 0; n < DS; ++n) {
            float dA = __expf(dtv * A[n]);
            h[n] = dA * h[n] + bx * Bsm[t][n];
        }
    }
#pragma unroll
    for (int n = 0; n < DS; ++n) {
        size_t o = ((size_t)bc * DS + n) * DI + d;
        hend[o] = h[n];
        prodA[o] = __expf(dtsum * A[n]);
    }
}

// Pass 2: sequential combine; reads hend/prodA, writes INCOMING states to hin.
__global__ __launch_bounds__(256) void scan_pass2(
    const float* __restrict__ hend, const float* __restrict__ prodA,
    float* __restrict__ hin)
{
    const int gid = blockIdx.x * 256 + threadIdx.x;  // (b*DS+n)*DI + d
    const int d = gid & (DI - 1);
    const int bn = gid >> 11;
    const int n = bn & (DS - 1);
    const int b = bn >> 4;
    float hprev = 0.f;
#pragma unroll 8
    for (int c = 0; c < NC; ++c) {
        size_t o = ((size_t)(b * NC + c) * DS + n) * DI + d;
        hin[o] = hprev;
        hprev = prodA[o] * hprev + hend[o];
    }
}

// Pass 3: re-scan each chunk from h_in; y, +x*D, *silu(res) -> yg (bf16).
__global__ __launch_bounds__(256) void scan_pass3(
    const float* __restrict__ dt, const ushort_t* __restrict__ xc,
    const float* __restrict__ xdbl, const ushort_t* __restrict__ res,
    const float* __restrict__ logA, const float* __restrict__ Dp,
    const float* __restrict__ hin, ushort_t* __restrict__ yg)
{
    __shared__ float BCs[CL][2 * DS];   // [t][0..15]=B, [t][16..31]=C
    const int bid = blockIdx.x;
    const int bc = bid >> 3;
    const int d = ((bid & 7) << 8) + threadIdx.x;
    const int c = bc & (NC - 1);
    const int b = bc >> 5;
    const int r0 = b * SEQ + c * CL;

    {   // stage B|C: CL x 32 floats, two float4/thread
        int i = threadIdx.x;
        int r = i >> 3, c4 = (i & 7) << 2;
        *(float4*)&BCs[r][c4] = *(const float4*)&xdbl[(size_t)(r0 + r) * XPC + DR + c4];
        int i2 = i + 256;
        int r2 = i2 >> 3, c42 = (i2 & 7) << 2;
        *(float4*)&BCs[r2][c42] = *(const float4*)&xdbl[(size_t)(r0 + r2) * XPC + DR + c42];
    }
    __syncthreads();

    float A[DS], h[DS];
#pragma unroll
    for (int n = 0; n < DS; ++n) {
        A[n] = -__expf(logA[d * DS + n]);
        h[n] = hin[((size_t)bc * DS + n) * DI + d];
    }
    const float Dd = Dp[d];
#pragma unroll 4
    for (int t = 0; t < CL; ++t) {
        const int r = r0 + t;
        float dtv = dt[(size_t)r * DI + d];
        float xv = bf2f(xc[(size_t)r * DI + d]);
        float bx = dtv * xv;
        float y = 0.f;
#pragma unroll
        for (int n = 0; n < DS; ++n) {
            float dA = __expf(dtv * A[n]);
            h[n] = dA * h[n] + bx * BCs[t][n];
            y += h[n] * BCs[t][DS + n];
        }
        y += xv * Dd;
        float rv = bf2f(res[(size_t)r * XRLD + d]);
        float sr = rv / (1.f + __expf(-rv));
        yg[(size_t)r * DI + d] = f2bf(y * sr);
    }
}

extern "C" void kernel_launch(void* const* d_in, const int* in_sizes, int n_in,
                              void* d_out, int out_size, void* d_ws, size_t ws_size,
                              hipStream_t stream) {
    const float* x          = (const float*)d_in[0];
    const float* in_proj_w  = (const float*)d_in[1];
    const float* in_proj_b  = (const float*)d_in[2];
    const float* conv_w     = (const float*)d_in[3];
    const float* conv_b     = (const float*)d_in[4];
    const float* x_proj_w   = (const float*)d_in[5];
    const float* dt_proj_w  = (const float*)d_in[6];
    const float* dt_proj_b  = (const float*)d_in[7];
    const float* log_A      = (const float*)d_in[8];
    const float* Dp         = (const float*)d_in[9];
    const float* out_proj_w = (const float*)d_in[10];
    const float* out_proj_b = (const float*)d_in[11];

    // Workspace layout (~143 MB)
    float* ws    = (float*)d_ws;
    float* dt    = ws;                            // ROWS*DI fp32 (32 MB); xproj partials overlay (12 MB)
    float* part  = ws;                            //   [KSXP][ROWS][XPC] fp32, dead before dt GEMM writes dt
    float* xdbl  = dt    + (size_t)ROWS * DI;     // ROWS*XPC fp32 (1.5 MB)
    float* hend  = xdbl  + (size_t)ROWS * XPC;    // 8 MB
    float* prodA = hend  + (size_t)BATCH * NC * DS * DI;  // 8 MB
    float* hin   = prodA + (size_t)BATCH * NC * DS * DI;  // 8 MB
    ushort_t* xr     = (ushort_t*)(hin + (size_t)BATCH * NC * DS * DI); // ROWS*XRLD bf16 (32 MB)
    ushort_t* xc_bf  = xr     + (size_t)ROWS * XRLD;      // ROWS*DI bf16 (16 MB)
    ushort_t* yg_bf  = xc_bf  + (size_t)ROWS * DI;        // ROWS*DI bf16 (16 MB)
    ushort_t* x_bf   = yg_bf  + (size_t)ROWS * DI;        // ROWS*DM bf16 (8 MB)
    ushort_t* wt_in  = x_bf   + (size_t)ROWS * DM;        // [2*DI][DM] bf16 (8 MB)
    ushort_t* wt_out = wt_in  + (size_t)2 * DI * DM;      // [DM][DI] bf16 (4 MB)
    ushort_t* wt_xp  = wt_out + (size_t)DM * DI;          // [XPC][DI] bf16 (0.4 MB)
    ushort_t* wt_dt  = wt_xp  + (size_t)XPC * DI;         // [DI][DR] bf16 (0.25 MB)
    ushort_t* xdt_bf = wt_dt  + (size_t)DI * DR;          // [ROWS][DR] bf16 (0.5 MB)

    dim3 blk(256);

    // 0) converts (once per launch)
    cvt_f32_bf16<<<(ROWS * DM / 4) / 256, blk, 0, stream>>>(x, x_bf);
    convt_bf16<<<dim3(2 * DI / 32, DM / 32), blk, 0, stream>>>(in_proj_w, wt_in, DM, 2 * DI);
    convt_bf16<<<dim3(DM / 32, DI / 32), blk, 0, stream>>>(out_proj_w, wt_out, DI, DM);
    convt_bf16<<<dim3(XPC / 32, DI / 32), blk, 0, stream>>>(x_proj_w, wt_xp, DI, XPC);
    convt_bf16<<<dim3(DI / 32, DR / 32), blk, 0, stream>>>(dt_proj_w, wt_dt, DR, DI);

    // 1) in_proj fused (N=4096): x_bf @ wt_in^T + b -> xr (bf16)
    gemm128_bt<1, ushort_t><<<dim3(XRLD / 128, ROWS / 128), blk, 0, stream>>>(
        x_bf, wt_in, in_proj_b, xr, DM, XRLD);

    // 2) conv + silu: xr[:,0:DI] -> xc (bf16)
    conv_silu_kernel<<<(ROWS * DI) / 256, blk, 0, stream>>>(xr, conv_w, conv_b, xc_bf);

    // 3) x_proj split-K: xc_bf @ wt_xp^T -> part -> xdbl (+ xdt_bf bf16 cols)
    xproj_splitk<<<dim3(KSXP, ROWS / 64), blk, 0, stream>>>(xc_bf, wt_xp, part, DI);
    xproj_reduce<<<(ROWS * XPC / 4) / 256, blk, 0, stream>>>(part, xdbl, xdt_bf);

    // 4) dt_proj as MFMA GEMM (K=64) + fused softplus: xdt_bf @ wt_dt^T -> dt (fp32)
    gemm128_bt<2, float><<<dim3(DI / 128, ROWS / 128), blk, 0, stream>>>(
        xdt_bf, wt_dt, dt_proj_b, dt, DR, DI);

    // 5) chunked selective scan
    scan_pass1<<<BATCH * NC * (DI / 256), blk, 0, stream>>>(
        dt, xc_bf, xdbl, log_A, hend, prodA);
    scan_pass2<<<(BATCH * DS * DI) / 256, blk, 0, stream>>>(hend, prodA, hin);
    scan_pass3<<<BATCH * NC * (DI / 256), blk, 0, stream>>>(
        dt, xc_bf, xdbl, xr + DI, log_A, Dp, hin, yg_bf);

    // 6) out_proj: yg_bf @ wt_out^T + b -> out (fp32)
    gemm128_bt<0, float><<<dim3(DM / 128, ROWS / 128), blk, 0, stream>>>(
        yg_bf, wt_out, out_proj_b, (float*)d_out, DI, DM);
}

// Round 11
// 277.470 us; speedup vs baseline: 9.0786x; 1.0354x over previous
//
#include <hip/hip_runtime.h>
#include <hip/hip_bf16.h>

// Problem constants
#define BATCH 2
#define SEQ 2048
#define DM 1024      // d_model
#define DI 2048      // d_inner
#define DS 16        // d_state
#define DR 64        // dt_rank
#define XPC 96       // dt_rank + 2*d_state
#define ROWS 4096    // BATCH*SEQ
#define NC 32        // scan chunks per sequence
#define CL 64        // chunk length = SEQ/NC
#define XRLD 4096    // ld of fused in_proj output (x_val | res), bf16
#define KSXP 8       // xproj split-K factor

typedef __attribute__((ext_vector_type(8))) short bf16x8;
typedef __attribute__((ext_vector_type(4))) float f32x4;
typedef unsigned short ushort_t;
typedef unsigned int u32;

#define GLD_LDS16(g, l) \
    __builtin_amdgcn_global_load_lds((const __attribute__((address_space(1))) u32*)(g), \
                                     (__attribute__((address_space(3))) u32*)(l), 16, 0, 0)

static __device__ __forceinline__ float bf2f(ushort_t u) {
    __hip_bfloat16 b = *(__hip_bfloat16*)&u;
    return __bfloat162float(b);
}
static __device__ __forceinline__ ushort_t f2bf(float f) {
    __hip_bfloat16 b = __float2bfloat16(f);
    return *(ushort_t*)&b;
}

// ---------------- fp32 -> bf16 elementwise convert ----------------
__global__ __launch_bounds__(256) void cvt_f32_bf16(
    const float* __restrict__ in, ushort_t* __restrict__ out)
{
    const size_t i = (size_t)(blockIdx.x * 256 + threadIdx.x) * 4;
    float4 v = *(const float4*)(in + i);
    ushort4 o;
    o.x = f2bf(v.x); o.y = f2bf(v.y); o.z = f2bf(v.z); o.w = f2bf(v.w);
    *(ushort4*)(out + i) = o;
}

// ------- merged transpose+convert for all 4 weights: W[K][N] fp32 -> Wt[N][K] bf16 -------
// segments: in_proj (1024x4096, 4096 blk), out_proj (2048x1024, 2048 blk),
//           x_proj (2048x96, 192 blk), dt_proj (64x2048, 128 blk). total 6464.
__global__ __launch_bounds__(256) void convt_multi(
    const float* __restrict__ ipw, ushort_t* __restrict__ wt_in,
    const float* __restrict__ opw, ushort_t* __restrict__ wt_out,
    const float* __restrict__ xpw, ushort_t* __restrict__ wt_xp,
    const float* __restrict__ dpw, ushort_t* __restrict__ wt_dt)
{
    __shared__ float t[32][33];
    int b = blockIdx.x;
    const float* W; ushort_t* Wt; int K, N, nb;
    if (b < 4096)      { W = ipw; Wt = wt_in;  K = 1024; N = 4096; nb = 128; }
    else if (b < 6144) { b -= 4096; W = opw; Wt = wt_out; K = 2048; N = 1024; nb = 32; }
    else if (b < 6336) { b -= 6144; W = xpw; Wt = wt_xp;  K = 2048; N = 96;   nb = 3;  }
    else               { b -= 6336; W = dpw; Wt = wt_dt;  K = 64;   N = 2048; nb = 64; }
    const int n0 = (b % nb) * 32, k0 = (b / nb) * 32;
    const int tx = threadIdx.x & 31, ty = threadIdx.x >> 5;  // 32 x 8
#pragma unroll
    for (int i = 0; i < 32; i += 8)
        t[ty + i][tx] = W[(size_t)(k0 + ty + i) * N + n0 + tx];
    __syncthreads();
#pragma unroll
    for (int i = 0; i < 32; i += 8)
        Wt[(size_t)(n0 + ty + i) * K + k0 + tx] = f2bf(t[tx][ty + i]);
}

// ---------------- 128x128 bf16 MFMA GEMM, 2-phase double-buffered staging ----------------
// C = A[M,K]bf16 @ Bt[N,K]bf16^T (+ epilogue per EPI).
// EPI: 0 = bias, fp32; 1 = bias, bf16; 2 = softplus(v+bias), fp32; 3 = softplus(v+bias), bf16.
// SPLITK: grid.x = nbx*SPLITK; block ks works K-slice [ks*K/SPLITK, ...) and writes
// partial matrix C + ks*M*ldc (bias should be nullptr for SPLITK>1).
template<int EPI, typename OutT, int SPLITK>
__global__ __launch_bounds__(256) void gemm128_bt(
    const ushort_t* __restrict__ A, const ushort_t* __restrict__ Bt,
    const float* __restrict__ bias, OutT* __restrict__ C,
    int K, int ldc)
{
    __shared__ ushort_t As[2][128 * 32];
    __shared__ ushort_t Bs[2][128 * 32];
    const int tid = threadIdx.x;
    const int lane = tid & 63, wid = tid >> 6;
    const int quad = lane >> 4, l16 = lane & 15;
    const int wr = wid >> 1, wc = wid & 1;
    const int nbx = gridDim.x / SPLITK;
    const int bn = blockIdx.x % nbx;
    const int ks = blockIdx.x / nbx;
    const int bm = blockIdx.y;
    const int ksl = K / SPLITK;
    const int kbeg = ks * ksl;
    OutT* Cb = C + (size_t)ks * (size_t)gridDim.y * 128 * ldc;

    const int sr = tid >> 2, sk = (tid & 3) << 3;
    const ushort_t* Ag0 = A + (size_t)(bm * 128 + sr) * K + kbeg + sk;
    const ushort_t* Ag1 = A + (size_t)(bm * 128 + 64 + sr) * K + kbeg + sk;
    const ushort_t* Bg0 = Bt + (size_t)(bn * 128 + sr) * K + kbeg + sk;
    const ushort_t* Bg1 = Bt + (size_t)(bn * 128 + 64 + sr) * K + kbeg + sk;

    f32x4 acc[4][4];
#pragma unroll
    for (int m = 0; m < 4; ++m)
#pragma unroll
        for (int n = 0; n < 4; ++n) acc[m][n] = (f32x4){0.f, 0.f, 0.f, 0.f};

    auto stage = [&](int buf, int kk) {
        GLD_LDS16(Ag0 + kk, &As[buf][tid * 8]);
        GLD_LDS16(Ag1 + kk, &As[buf][(tid + 256) * 8]);
        GLD_LDS16(Bg0 + kk, &Bs[buf][tid * 8]);
        GLD_LDS16(Bg1 + kk, &Bs[buf][(tid + 256) * 8]);
    };
    auto compute = [&](int buf) {
        bf16x8 a[4], b[4];
#pragma unroll
        for (int m = 0; m < 4; ++m)
            a[m] = *(const bf16x8*)&As[buf][(wr * 64 + m * 16 + l16) * 32 + 8 * quad];
#pragma unroll
        for (int n = 0; n < 4; ++n)
            b[n] = *(const bf16x8*)&Bs[buf][(wc * 64 + n * 16 + l16) * 32 + 8 * quad];
#pragma unroll
        for (int m = 0; m < 4; ++m)
#pragma unroll
            for (int n = 0; n < 4; ++n)
                acc[m][n] = __builtin_amdgcn_mfma_f32_16x16x32_bf16(
                    a[m], b[n], acc[m][n], 0, 0, 0);
    };

    const int nt = ksl >> 5;          // K-steps in this slice (even for all our shapes)
    stage(0, 0);
    for (int t = 0; t < nt; t += 2) {
        __syncthreads();              // buf0 staged; prev reads of buf1 done
        if (t + 1 < nt) stage(1, (t + 1) << 5);
        compute(0);
        __syncthreads();              // buf1 staged; reads of buf0 done
        if (t + 2 < nt) stage(0, (t + 2) << 5);
        compute(1);
    }

#pragma unroll
    for (int m = 0; m < 4; ++m) {
        const int row0 = bm * 128 + wr * 64 + m * 16 + quad * 4;
#pragma unroll
        for (int n = 0; n < 4; ++n) {
            const int col = bn * 128 + wc * 64 + n * 16 + l16;
            const float bv = bias ? bias[col] : 0.f;
#pragma unroll
            for (int r = 0; r < 4; ++r) {
                float v = acc[m][n][r] + bv;
                if constexpr (EPI == 1) {
                    ((ushort_t*)Cb)[(size_t)(row0 + r) * ldc + col] = f2bf(v);
                } else if constexpr (EPI == 2) {
                    float sp = (v > 20.f) ? v : log1pf(__expf(v));
                    ((float*)Cb)[(size_t)(row0 + r) * ldc + col] = sp;
                } else if constexpr (EPI == 3) {
                    float sp = (v > 20.f) ? v : log1pf(__expf(v));
                    ((ushort_t*)Cb)[(size_t)(row0 + r) * ldc + col] = f2bf(sp);
                } else {
                    ((float*)Cb)[(size_t)(row0 + r) * ldc + col] = v;
                }
            }
        }
    }
}

// sum 2 split-K partials + bias -> fp32 out (for out_proj)
__global__ __launch_bounds__(256) void sum2_bias(
    const float* __restrict__ part, const float* __restrict__ bias,
    float* __restrict__ out)
{
    const size_t i = (size_t)(blockIdx.x * 256 + threadIdx.x) * 4;
    float4 a = *(const float4*)(part + i);
    float4 b = *(const float4*)(part + (size_t)ROWS * DM + i);
    float4 bv = *(const float4*)(bias + (i & (DM - 1)));
    float4 o;
    o.x = a.x + b.x + bv.x; o.y = a.y + b.y + bv.y;
    o.z = a.z + b.z + bv.z; o.w = a.w + b.w + bv.w;
    *(float4*)(out + i) = o;
}

// ---------------- split-K x_proj GEMM: 64x96 tile, K slice per blockIdx.x ----------------
__global__ __launch_bounds__(256) void xproj_splitk(
    const ushort_t* __restrict__ A, const ushort_t* __restrict__ Bt,
    float* __restrict__ part, int K)
{
    const int BM = 64, BN = XPC;
    __shared__ ushort_t As[64 * 40];
    __shared__ ushort_t Bs[XPC * 40];
    const int tid = threadIdx.x;
    const int wid = tid >> 6, lane = tid & 63;
    const int quad = lane >> 4, l16 = lane & 15;
    const int wr = wid;          // WM=4, WN=1
    const int bm = blockIdx.y;
    const int ks = blockIdx.x;
    const int kslc = K / KSXP;   // 256
    const int kbeg = ks * kslc;

    f32x4 acc[6];
#pragma unroll
    for (int n = 0; n < 6; ++n) acc[n] = (f32x4){0.f, 0.f, 0.f, 0.f};

    for (int k0 = kbeg; k0 < kbeg + kslc; k0 += 32) {
        for (int i = tid; i < BM * 4; i += 256) {
            int r = i >> 2, kk = (i & 3) << 3;
            *(uint4*)&As[r * 40 + kk] =
                *(const uint4*)&A[(size_t)(bm * BM + r) * K + k0 + kk];
        }
        for (int i = tid; i < BN * 4; i += 256) {
            int r = i >> 2, kk = (i & 3) << 3;
            *(uint4*)&Bs[r * 40 + kk] =
                *(const uint4*)&Bt[(size_t)r * K + k0 + kk];
        }
        __syncthreads();
        bf16x8 a, b[6];
        a = *(const bf16x8*)&As[(wr * 16 + l16) * 40 + 8 * quad];
#pragma unroll
        for (int n = 0; n < 6; ++n)
            b[n] = *(const bf16x8*)&Bs[(n * 16 + l16) * 40 + 8 * quad];
#pragma unroll
        for (int n = 0; n < 6; ++n)
            acc[n] = __builtin_amdgcn_mfma_f32_16x16x32_bf16(a, b[n], acc[n], 0, 0, 0);
        __syncthreads();
    }

    float* out = part + (size_t)ks * ROWS * XPC;
    const int row0 = bm * BM + wr * 16 + quad * 4;
#pragma unroll
    for (int n = 0; n < 6; ++n) {
        const int col = n * 16 + l16;
#pragma unroll
        for (int r = 0; r < 4; ++r)
            out[(size_t)(row0 + r) * XPC + col] = acc[n][r];
    }
}

// sum the KSXP partials -> xdbl (fp32) ; also emit cols 0..DR-1 as bf16 (xdt)
__global__ __launch_bounds__(256) void xproj_reduce(
    const float* __restrict__ part, float* __restrict__ xdbl,
    ushort_t* __restrict__ xdt)
{
    const size_t i = (size_t)(blockIdx.x * 256 + threadIdx.x) * 4;
    float4 s = *(const float4*)(part + i);
#pragma unroll
    for (int ks = 1; ks < KSXP; ++ks) {
        float4 v = *(const float4*)(part + (size_t)ks * ROWS * XPC + i);
        s.x += v.x; s.y += v.y; s.z += v.z; s.w += v.w;
    }
    *(float4*)(xdbl + i) = s;
    const int col = (int)(i % XPC);
    if (col < DR) {
        const int row = (int)(i / XPC);
        ushort4 o;
        o.x = f2bf(s.x); o.y = f2bf(s.y); o.z = f2bf(s.z); o.w = f2bf(s.w);
        *(ushort4*)(xdt + (size_t)row * DR + col) = o;
    }
}

// ---------------- depthwise causal conv (width 4) + SiLU -> bf16, 4 d's/thread ----------------
__global__ __launch_bounds__(256) void conv_silu_kernel(
    const ushort_t* __restrict__ xr, const float* __restrict__ cw,
    const float* __restrict__ cb, ushort_t* __restrict__ xc)
{
    const int i = blockIdx.x * 256 + threadIdx.x;   // over ROWS*DI/4
    const int r = i >> 9;                           // /(DI/4)
    const int d0 = (i & 511) << 2;
    const int t = r & (SEQ - 1);
    float w[4][4];                                  // [j][tap]
#pragma unroll
    for (int j = 0; j < 4; ++j)
        *(float4*)w[j] = *(const float4*)&cw[(d0 + j) * 4];
    float4 bb = *(const float4*)&cb[d0];
    float acc[4] = {bb.x, bb.y, bb.z, bb.w};
#pragma unroll
    for (int k = 0; k < 4; ++k) {
        int tt = t - 3 + k;
        if (tt >= 0) {
            ushort4 v = *(const ushort4*)&xr[(size_t)(r - 3 + k) * XRLD + d0];
            acc[0] += bf2f(v.x) * w[0][k];
            acc[1] += bf2f(v.y) * w[1][k];
            acc[2] += bf2f(v.z) * w[2][k];
            acc[3] += bf2f(v.w) * w[3][k];
        }
    }
    ushort4 o;
    o.x = f2bf(acc[0] / (1.f + __expf(-acc[0])));
    o.y = f2bf(acc[1] / (1.f + __expf(-acc[1])));
    o.z = f2bf(acc[2] / (1.f + __expf(-acc[2])));
    o.w = f2bf(acc[3] / (1.f + __expf(-acc[3])));
    *(ushort4*)&xc[(size_t)r * DI + d0] = o;
}

// ---------------- chunked selective scan (dt is bf16 now) ----------------

// Pass 1: local scan from 0; store hend and prodA.
__global__ __launch_bounds__(256) void scan_pass1(
    const ushort_t* __restrict__ dt, const ushort_t* __restrict__ xc,
    const float* __restrict__ xdbl, const float* __restrict__ logA,
    float* __restrict__ hend, float* __restrict__ prodA)
{
    __shared__ float Bsm[CL][DS];
    const int bid = blockIdx.x;
    const int bc = bid >> 3;                       // b*NC + c
    const int d = ((bid & 7) << 8) + threadIdx.x;
    const int c = bc & (NC - 1);
    const int b = bc >> 5;
    const int r0 = b * SEQ + c * CL;

    {   // stage B: CL x 16 floats, one float4/thread
        int i = threadIdx.x;
        int r = i >> 2, n4 = (i & 3) << 2;
        *(float4*)&Bsm[r][n4] = *(const float4*)&xdbl[(size_t)(r0 + r) * XPC + DR + n4];
    }
    __syncthreads();

    float A[DS], h[DS];
#pragma unroll
    for (int n = 0; n < DS; ++n) {
        A[n] = -__expf(logA[d * DS + n]);
        h[n] = 0.f;
    }
    float dtsum = 0.f;
#pragma unroll 4
    for (int t = 0; t < CL; ++t) {
        const int r = r0 + t;
        float dtv = bf2f(dt[(size_t)r * DI + d]);
        float xv = bf2f(xc[(size_t)r * DI + d]);
        float bx = dtv * xv;
        dtsum += dtv;
#pragma unroll
        for (int n = 0; n < DS; ++n) {
            float dA = __expf(dtv * A[n]);
            h[n] = dA * h[n] + bx * Bsm[t][n];
        }
    }
#pragma unroll
    for (int n = 0; n < DS; ++n) {
        size_t o = ((size_t)bc * DS + n) * DI + d;
        hend[o] = h[n];
        prodA[o] = __expf(dtsum * A[n]);
    }
}

// Pass 2: sequential combine; reads hend/prodA, writes INCOMING states to hin.
__global__ __launch_bounds__(256) void scan_pass2(
    const float* __restrict__ hend, const float* __restrict__ prodA,
    float* __restrict__ hin)
{
    const int gid = blockIdx.x * 256 + threadIdx.x;  // (b*DS+n)*DI + d
    const int d = gid & (DI - 1);
    const int bn = gid >> 11;
    const int n = bn & (DS - 1);
    const int b = bn >> 4;
    float hprev = 0.f;
#pragma unroll 8
    for (int c = 0; c < NC; ++c) {
        size_t o = ((size_t)(b * NC + c) * DS + n) * DI + d;
        hin[o] = hprev;
        hprev = prodA[o] * hprev + hend[o];
    }
}

// Pass 3: re-scan each chunk from h_in; y, +x*D, *silu(res) -> yg (bf16).
__global__ __launch_bounds__(256) void scan_pass3(
    const ushort_t* __restrict__ dt, const ushort_t* __restrict__ xc,
    const float* __restrict__ xdbl, const ushort_t* __restrict__ res,
    const float* __restrict__ logA, const float* __restrict__ Dp,
    const float* __restrict__ hin, ushort_t* __restrict__ yg)
{
    __shared__ float BCs[CL][2 * DS];   // [t][0..15]=B, [t][16..31]=C
    const int bid = blockIdx.x;
    const int bc = bid >> 3;
    const int d = ((bid & 7) << 8) + threadIdx.x;
    const int c = bc & (NC - 1);
    const int b = bc >> 5;
    const int r0 = b * SEQ + c * CL;

    {   // stage B|C: CL x 32 floats, two float4/thread
        int i = threadIdx.x;
        int r = i >> 3, c4 = (i & 7) << 2;
        *(float4*)&BCs[r][c4] = *(const float4*)&xdbl[(size_t)(r0 + r) * XPC + DR + c4];
        int i2 = i + 256;
        int r2 = i2 >> 3, c42 = (i2 & 7) << 2;
        *(float4*)&BCs[r2][c42] = *(const float4*)&xdbl[(size_t)(r0 + r2) * XPC + DR + c42];
    }
    __syncthreads();

    float A[DS], h[DS];
#pragma unroll
    for (int n = 0; n < DS; ++n) {
        A[n] = -__expf(logA[d * DS + n]);
        h[n] = hin[((size_t)bc * DS + n) * DI + d];
    }
    const float Dd = Dp[d];
#pragma unroll 4
    for (int t = 0; t < CL; ++t) {
        const int r = r0 + t;
        float dtv = bf2f(dt[(size_t)r * DI + d]);
        float xv = bf2f(xc[(size_t)r * DI + d]);
        float bx = dtv * xv;
        float y = 0.f;
#pragma unroll
        for (int n = 0; n < DS; ++n) {
            float dA = __expf(dtv * A[n]);
            h[n] = dA * h[n] + bx * BCs[t][n];
            y += h[n] * BCs[t][DS + n];
        }
        y += xv * Dd;
        float rv = bf2f(res[(size_t)r * XRLD + d]);
        float sr = rv / (1.f + __expf(-rv));
        yg[(size_t)r * DI + d] = f2bf(y * sr);
    }
}

extern "C" void kernel_launch(void* const* d_in, const int* in_sizes, int n_in,
                              void* d_out, int out_size, void* d_ws, size_t ws_size,
                              hipStream_t stream) {
    const float* x          = (const float*)d_in[0];
    const float* in_proj_w  = (const float*)d_in[1];
    const float* in_proj_b  = (const float*)d_in[2];
    const float* conv_w     = (const float*)d_in[3];
    const float* conv_b     = (const float*)d_in[4];
    const float* x_proj_w   = (const float*)d_in[5];
    const float* dt_proj_w  = (const float*)d_in[6];
    const float* dt_proj_b  = (const float*)d_in[7];
    const float* log_A      = (const float*)d_in[8];
    const float* Dp         = (const float*)d_in[9];
    const float* out_proj_w = (const float*)d_in[10];
    const float* out_proj_b = (const float*)d_in[11];

    // Workspace layout (~143 MB, unchanged footprint)
    float* ws    = (float*)d_ws;
    // region0 (32 MB): xproj partials (12.6 MB, step 3) then dt bf16 (16 MB, step 4+)
    float*    part  = ws;
    ushort_t* dt_bf = (ushort_t*)ws;
    float* xdbl  = ws    + (size_t)ROWS * DI;             // ROWS*XPC fp32 (1.5 MB)
    float* hend  = xdbl  + (size_t)ROWS * XPC;            // 8 MB
    float* prodA = hend  + (size_t)BATCH * NC * DS * DI;  // 8 MB
    float* hin   = prodA + (size_t)BATCH * NC * DS * DI;  // 8 MB
    // out_proj split-K partials (32 MB) overlay hend+prodA+hin+first 8MB of xr
    // (all dead by out_proj time)
    float* part_out = hend;
    ushort_t* xr     = (ushort_t*)(hin + (size_t)BATCH * NC * DS * DI); // ROWS*XRLD bf16 (32 MB)
    ushort_t* xc_bf  = xr     + (size_t)ROWS * XRLD;      // ROWS*DI bf16 (16 MB)
    ushort_t* yg_bf  = xc_bf  + (size_t)ROWS * DI;        // ROWS*DI bf16 (16 MB)
    ushort_t* x_bf   = yg_bf  + (size_t)ROWS * DI;        // ROWS*DM bf16 (8 MB)
    ushort_t* wt_in  = x_bf   + (size_t)ROWS * DM;        // [2*DI][DM] bf16 (8 MB)
    ushort_t* wt_out = wt_in  + (size_t)2 * DI * DM;      // [DM][DI] bf16 (4 MB)
    ushort_t* wt_xp  = wt_out + (size_t)DM * DI;          // [XPC][DI] bf16 (0.4 MB)
    ushort_t* wt_dt  = wt_xp  + (size_t)XPC * DI;         // [DI][DR] bf16 (0.25 MB)
    ushort_t* xdt_bf = wt_dt  + (size_t)DI * DR;          // [ROWS][DR] bf16 (0.5 MB)

    dim3 blk(256);

    // 0) converts (once per launch): x -> bf16, all weights transposed+converted
    cvt_f32_bf16<<<(ROWS * DM / 4) / 256, blk, 0, stream>>>(x, x_bf);
    convt_multi<<<6464, blk, 0, stream>>>(in_proj_w, wt_in, out_proj_w, wt_out,
                                          x_proj_w, wt_xp, dt_proj_w, wt_dt);

    // 1) in_proj fused (N=4096): x_bf @ wt_in^T + b -> xr (bf16)
    gemm128_bt<1, ushort_t, 1><<<dim3(XRLD / 128, ROWS / 128), blk, 0, stream>>>(
        x_bf, wt_in, in_proj_b, xr, DM, XRLD);

    // 2) conv + silu: xr[:,0:DI] -> xc (bf16), vectorized x4
    conv_silu_kernel<<<(ROWS * DI / 4) / 256, blk, 0, stream>>>(xr, conv_w, conv_b, xc_bf);

    // 3) x_proj split-K: xc_bf @ wt_xp^T -> part -> xdbl (+ xdt_bf bf16 cols)
    xproj_splitk<<<dim3(KSXP, ROWS / 64), blk, 0, stream>>>(xc_bf, wt_xp, part, DI);
    xproj_reduce<<<(ROWS * XPC / 4) / 256, blk, 0, stream>>>(part, xdbl, xdt_bf);

    // 4) dt_proj as MFMA GEMM (K=64) + fused softplus -> dt (bf16)
    gemm128_bt<3, ushort_t, 1><<<dim3(DI / 128, ROWS / 128), blk, 0, stream>>>(
        xdt_bf, wt_dt, dt_proj_b, dt_bf, DR, DI);

    // 5) chunked selective scan
    scan_pass1<<<BATCH * NC * (DI / 256), blk, 0, stream>>>(
        dt_bf, xc_bf, xdbl, log_A, hend, prodA);
    scan_pass2<<<(BATCH * DS * DI) / 256, blk, 0, stream>>>(hend, prodA, hin);
    scan_pass3<<<BATCH * NC * (DI / 256), blk, 0, stream>>>(
        dt_bf, xc_bf, xdbl, xr + DI, log_A, Dp, hin, yg_bf);

    // 6) out_proj split-K=2 (512 blocks): yg_bf @ wt_out^T -> part_out; then +bias
    gemm128_bt<0, float, 2><<<dim3(2 * DM / 128, ROWS / 128), blk, 0, stream>>>(
        yg_bf, wt_out, nullptr, part_out, DI, DM);
    sum2_bias<<<(ROWS * DM / 4) / 256, blk, 0, stream>>>(
        part_out, out_proj_b, (float*)d_out);
}